// Round 4
// baseline (10697.581 us; speedup 1.0000x reference)
//
#include <hip/hip_runtime.h>

#define EPS 1e-12f

constexpr int H = 768, W = 768, C = 3;
constexpr int HW = H * W;
constexpr int CHW = C * HW;

constexpr int NSLOT = 16;              // hashed atomic slots per scalar
constexpr int SSTR = 16;               // slot spacing (64B)
constexpr int SCALSZ = NSLOT * SSTR;

// LDS tile geometry (output tile 64x32, 256 threads, 8 px/thread)
constexpr int SPW = 100, SPH = 60;     // p-tile: origin (-14,-14), 96 cols staged
constexpr int S0W = 84,  S0H = 46;     // t0-tile: origin (-7,-7), 78 valid cols (80 written)
constexpr int S1W = 76,  S1H = 36;     // t1/t2-tile: origin (-2,-2), 68 valid cols (72 written)

__device__ __forceinline__ float block_reduce_256(float v, float* redbuf) {
    #pragma unroll
    for (int off = 32; off > 0; off >>= 1) v += __shfl_down(v, off, 64);
    const int tid = threadIdx.x;
    if ((tid & 63) == 0) redbuf[tid >> 6] = v;
    __syncthreads();
    return redbuf[0] + redbuf[1] + redbuf[2] + redbuf[3];
}

__device__ __forceinline__ float sum_slots(const float* base, int c) {
    float s = 0.f;
    #pragma unroll
    for (int k = 0; k < NSLOT; ++k) s += base[k * SSTR + c];
    return s;
}

// Fused A-apply. MODE 0: prologue (in=img): r0 = corrT15(img) - A(img); writes outR,outP(=r0),outX(=img); red += ||r0||^2
// MODE 1: iter 0 (in=p0): Ap = A(p0); red += p.Ap
// MODE 2: iter>=1 (in=p_prev, rvec=r): pe = r + beta*p_prev (incl. halo recompute); Ap = A(pe); pe->outP; red += pe.Ap
template <int MODE>
__global__ __launch_bounds__(256) void fusedA_k(
    const float* __restrict__ in, const float* __restrict__ rvec,
    const float* __restrict__ k15, const float* __restrict__ rks,
    const float* __restrict__ rw,
    float* __restrict__ Ap, float* __restrict__ outR,
    float* __restrict__ outP, float* __restrict__ outX,
    const float* __restrict__ bnum, const float* __restrict__ bden,
    float* __restrict__ red)
{
    __shared__ __align__(16) float sp[SPH * SPW];
    __shared__ __align__(16) float st0[S0H * S0W];
    __shared__ __align__(16) float st1[S1H * S1W];
    __shared__ __align__(16) float st2[S1H * S1W];
    __shared__ __align__(16) float kt[240], ktf[240];
    __shared__ __align__(16) float rkt[80], rktf[80];
    __shared__ float redbuf[4];

    const int c = blockIdx.z;
    const int bx = blockIdx.x * 64, by = blockIdx.y * 32;
    const int tid = threadIdx.x;
    const float* inC = in + c * HW;

    float beta = 0.f;
    if (MODE == 2) beta = sum_slots(bnum, c) / (sum_slots(bden, c) + EPS);

    // taps: forward + flipped, rows padded to 16/8 floats
    if (tid < 240) {
        const int i = tid >> 4, j = tid & 15;
        kt[tid]  = (j < 15) ? k15[i * 15 + j] : 0.f;
        ktf[tid] = (j < 15) ? k15[(14 - i) * 15 + (14 - j)] : 0.f;
    }
    if (tid < 80) {
        const int kk = tid / 40, rem = tid % 40, i = rem >> 3, j = rem & 7;
        rkt[tid]  = (j < 5) ? rks[kk * 25 + i * 5 + j] : 0.f;
        rktf[tid] = (j < 5) ? rks[kk * 25 + (4 - i) * 5 + (4 - j)] : 0.f;
    }

    // stage pe tile (halo 14), 60 rows x 96 cols
    for (int t = tid; t < SPH * 96; t += 256) {
        const int ly = t / 96, lx = t - ly * 96;
        const int gy = by - 14 + ly, gx = bx - 14 + lx;
        float v = 0.f;
        if ((unsigned)gy < (unsigned)H && (unsigned)gx < (unsigned)W) {
            const int g = gy * W + gx;
            v = inC[g];
            if (MODE == 2) v = rvec[c * HW + g] + beta * v;
        }
        sp[ly * SPW + lx] = v;
    }
    __syncthreads();

    // ---- phase 1a: t0 = corr15(pe) on 46 x 80 (78 valid), zero outside image grid ----
    for (int s = tid; s < 460; s += 256) {
        const int row = s / 10;
        const int col8 = (s - row * 10) << 3;
        float acc[8];
        #pragma unroll
        for (int k = 0; k < 8; ++k) acc[k] = 0.f;
        #pragma unroll 1
        for (int i = 0; i < 15; ++i) {
            const float* rowp = sp + (row + i) * SPW + col8;
            float seg[24];
            #pragma unroll
            for (int q = 0; q < 6; ++q) *(float4*)(seg + 4 * q) = *(const float4*)(rowp + 4 * q);
            float kv[16];
            #pragma unroll
            for (int q = 0; q < 4; ++q) *(float4*)(kv + 4 * q) = *(const float4*)(kt + i * 16 + 4 * q);
            #pragma unroll
            for (int j = 0; j < 15; ++j)
                #pragma unroll
                for (int k = 0; k < 8; ++k) acc[k] = fmaf(seg[j + k], kv[j], acc[k]);
        }
        const int gy = by - 7 + row, gxb = bx - 7 + col8;
        if ((unsigned)gy >= (unsigned)H) {
            #pragma unroll
            for (int k = 0; k < 8; ++k) acc[k] = 0.f;
        } else {
            #pragma unroll
            for (int k = 0; k < 8; ++k)
                if ((unsigned)(gxb + k) >= (unsigned)W) acc[k] = 0.f;
        }
        float* o = st0 + row * S0W + col8;
        *(float4*)(o)     = make_float4(acc[0], acc[1], acc[2], acc[3]);
        *(float4*)(o + 4) = make_float4(acc[4], acc[5], acc[6], acc[7]);
    }

    // ---- phase 1b: t1,t2 = corr5(pe) on 36 x 72 (68 valid), zero outside image grid ----
    for (int s = tid; s < 324; s += 256) {
        const int row = s / 9;
        const int col8 = (s - row * 9) << 3;
        float accB[8], accC[8];
        #pragma unroll
        for (int k = 0; k < 8; ++k) { accB[k] = 0.f; accC[k] = 0.f; }
        #pragma unroll 1
        for (int i = 0; i < 5; ++i) {
            const float* rowp = sp + (row + 10 + i) * SPW + col8 + 8;
            float seg[16];
            #pragma unroll
            for (int q = 0; q < 4; ++q) *(float4*)(seg + 4 * q) = *(const float4*)(rowp + 4 * q);
            float kb[8], kc[8];
            *(float4*)(kb)     = *(const float4*)(rkt + i * 8);
            *(float4*)(kb + 4) = *(const float4*)(rkt + i * 8 + 4);
            *(float4*)(kc)     = *(const float4*)(rkt + 40 + i * 8);
            *(float4*)(kc + 4) = *(const float4*)(rkt + 40 + i * 8 + 4);
            #pragma unroll
            for (int j = 0; j < 5; ++j)
                #pragma unroll
                for (int k = 0; k < 8; ++k) {
                    accB[k] = fmaf(seg[j + k + 2], kb[j], accB[k]);
                    accC[k] = fmaf(seg[j + k + 2], kc[j], accC[k]);
                }
        }
        const int gy = by - 2 + row, gxb = bx - 2 + col8;
        if ((unsigned)gy >= (unsigned)H) {
            #pragma unroll
            for (int k = 0; k < 8; ++k) { accB[k] = 0.f; accC[k] = 0.f; }
        } else {
            #pragma unroll
            for (int k = 0; k < 8; ++k)
                if ((unsigned)(gxb + k) >= (unsigned)W) { accB[k] = 0.f; accC[k] = 0.f; }
        }
        float* o1 = st1 + row * S1W + col8;
        float* o2 = st2 + row * S1W + col8;
        *(float4*)(o1)     = make_float4(accB[0], accB[1], accB[2], accB[3]);
        *(float4*)(o1 + 4) = make_float4(accB[4], accB[5], accB[6], accB[7]);
        *(float4*)(o2)     = make_float4(accC[0], accC[1], accC[2], accC[3]);
        *(float4*)(o2 + 4) = make_float4(accC[4], accC[5], accC[6], accC[7]);
    }
    __syncthreads();

    // ---- phase 2: adjoint convs -> 64x32 output tile ----
    const int oy = tid >> 3;
    const int ox = (tid & 7) << 3;

    float acc[8];
    #pragma unroll
    for (int k = 0; k < 8; ++k) acc[k] = 0.f;
    #pragma unroll 1
    for (int i = 0; i < 15; ++i) {
        const float* rowp = st0 + (oy + i) * S0W + ox;
        float seg[24];
        #pragma unroll
        for (int q = 0; q < 6; ++q) *(float4*)(seg + 4 * q) = *(const float4*)(rowp + 4 * q);
        float kv[16];
        #pragma unroll
        for (int q = 0; q < 4; ++q) *(float4*)(kv + 4 * q) = *(const float4*)(ktf + i * 16 + 4 * q);
        #pragma unroll
        for (int j = 0; j < 15; ++j)
            #pragma unroll
            for (int k = 0; k < 8; ++k) acc[k] = fmaf(seg[j + k], kv[j], acc[k]);
    }

    float accB[8], accC[8];
    #pragma unroll
    for (int k = 0; k < 8; ++k) { accB[k] = 0.f; accC[k] = 0.f; }
    #pragma unroll 1
    for (int i = 0; i < 5; ++i) {
        const float* r1p = st1 + (oy + i) * S1W + ox;
        const float* r2p = st2 + (oy + i) * S1W + ox;
        float sA[12], sB[12];
        #pragma unroll
        for (int q = 0; q < 3; ++q) *(float4*)(sA + 4 * q) = *(const float4*)(r1p + 4 * q);
        #pragma unroll
        for (int q = 0; q < 3; ++q) *(float4*)(sB + 4 * q) = *(const float4*)(r2p + 4 * q);
        float kb[8], kc[8];
        *(float4*)(kb)     = *(const float4*)(rktf + i * 8);
        *(float4*)(kb + 4) = *(const float4*)(rktf + i * 8 + 4);
        *(float4*)(kc)     = *(const float4*)(rktf + 40 + i * 8);
        *(float4*)(kc + 4) = *(const float4*)(rktf + 40 + i * 8 + 4);
        #pragma unroll
        for (int j = 0; j < 5; ++j)
            #pragma unroll
            for (int k = 0; k < 8; ++k) {
                accB[k] = fmaf(sA[j + k], kb[j], accB[k]);
                accC[k] = fmaf(sB[j + k], kc[j], accC[k]);
            }
    }

    float vimg[8];
    if (MODE == 0) {
        #pragma unroll
        for (int k = 0; k < 8; ++k) vimg[k] = 0.f;
        #pragma unroll 1
        for (int i = 0; i < 15; ++i) {
            const float* rowp = sp + (oy + 7 + i) * SPW + ox + 4;
            float seg[28];
            #pragma unroll
            for (int q = 0; q < 7; ++q) *(float4*)(seg + 4 * q) = *(const float4*)(rowp + 4 * q);
            float kv[16];
            #pragma unroll
            for (int q = 0; q < 4; ++q) *(float4*)(kv + 4 * q) = *(const float4*)(ktf + i * 16 + 4 * q);
            #pragma unroll
            for (int j = 0; j < 15; ++j)
                #pragma unroll
                for (int k = 0; k < 8; ++k) vimg[k] = fmaf(seg[j + k + 3], kv[j], vimg[k]);
        }
    }

    const float w0 = rw[0], w1 = rw[1];
    const float w02 = w0 * w0, w12 = w1 * w1;
    float v[8];
    #pragma unroll
    for (int k = 0; k < 8; ++k) v[k] = acc[k] + w02 * accB[k] + w12 * accC[k];

    const int g = c * HW + (by + oy) * W + bx + ox;
    const float* ctr = sp + (oy + 14) * SPW + ox + 14;  // pe center values
    float local = 0.f;
    if (MODE == 0) {
        #pragma unroll
        for (int k = 0; k < 8; ++k) v[k] = vimg[k] - v[k];
        *(float4*)(outR + g)     = make_float4(v[0], v[1], v[2], v[3]);
        *(float4*)(outR + g + 4) = make_float4(v[4], v[5], v[6], v[7]);
        *(float4*)(outP + g)     = make_float4(v[0], v[1], v[2], v[3]);
        *(float4*)(outP + g + 4) = make_float4(v[4], v[5], v[6], v[7]);
        *(float4*)(outX + g)     = make_float4(ctr[0], ctr[1], ctr[2], ctr[3]);
        *(float4*)(outX + g + 4) = make_float4(ctr[4], ctr[5], ctr[6], ctr[7]);
        #pragma unroll
        for (int k = 0; k < 8; ++k) local += v[k] * v[k];
    } else {
        *(float4*)(Ap + g)     = make_float4(v[0], v[1], v[2], v[3]);
        *(float4*)(Ap + g + 4) = make_float4(v[4], v[5], v[6], v[7]);
        #pragma unroll
        for (int k = 0; k < 8; ++k) local += ctr[k] * v[k];
        if (MODE == 2) {
            *(float4*)(outP + g)     = make_float4(ctr[0], ctr[1], ctr[2], ctr[3]);
            *(float4*)(outP + g + 4) = make_float4(ctr[4], ctr[5], ctr[6], ctr[7]);
        }
    }
    const float tot = block_reduce_256(local, redbuf);
    if (tid == 0) {
        const int bid = blockIdx.y * gridDim.x + blockIdx.x;
        atomicAdd(red + (bid & (NSLOT - 1)) * SSTR + c, tot);
    }
}

// x += alpha*p; r -= alpha*Ap; accumulate ||r_new||^2
__global__ __launch_bounds__(256) void cg_update_k(
    float* __restrict__ x, float* __restrict__ r,
    const float* __restrict__ Ap, const float* __restrict__ p,
    const float* __restrict__ rtr_cur, const float* __restrict__ ptap,
    float* __restrict__ rtr_next)
{
    __shared__ float redbuf[4];
    const int c = blockIdx.z;
    const float n = sum_slots(rtr_cur, c), d = sum_slots(ptap, c);
    const float alpha = n / (d + EPS);
    const int idx = c * HW + (blockIdx.x * 256 + threadIdx.x) * 8;
    float local = 0.f;
    #pragma unroll
    for (int h = 0; h < 2; ++h) {
        const int o = idx + 4 * h;
        float4 xv = *(float4*)(x + o);
        float4 rv = *(float4*)(r + o);
        const float4 pv = *(const float4*)(p + o);
        const float4 av = *(const float4*)(Ap + o);
        xv.x = fmaf(alpha, pv.x, xv.x); rv.x = fmaf(-alpha, av.x, rv.x);
        xv.y = fmaf(alpha, pv.y, xv.y); rv.y = fmaf(-alpha, av.y, rv.y);
        xv.z = fmaf(alpha, pv.z, xv.z); rv.z = fmaf(-alpha, av.z, rv.z);
        xv.w = fmaf(alpha, pv.w, xv.w); rv.w = fmaf(-alpha, av.w, rv.w);
        *(float4*)(x + o) = xv;
        *(float4*)(r + o) = rv;
        local += rv.x * rv.x + rv.y * rv.y + rv.z * rv.z + rv.w * rv.w;
    }
    const float tot = block_reduce_256(local, redbuf);
    if (threadIdx.x == 0)
        atomicAdd(rtr_next + ((int)blockIdx.x & (NSLOT - 1)) * SSTR + c, tot);
}

// final: p = r + beta*p99
__global__ __launch_bounds__(256) void p_final_k(
    const float* __restrict__ r, const float* __restrict__ p99, float* __restrict__ pout,
    const float* __restrict__ num, const float* __restrict__ den)
{
    const int c = blockIdx.z;
    const float beta = sum_slots(num, c) / (sum_slots(den, c) + EPS);
    const int idx = c * HW + (blockIdx.x * 256 + threadIdx.x) * 8;
    #pragma unroll
    for (int h = 0; h < 2; ++h) {
        const int o = idx + 4 * h;
        const float4 rv = *(const float4*)(r + o);
        const float4 pv = *(const float4*)(p99 + o);
        *(float4*)(pout + o) = make_float4(
            fmaf(beta, pv.x, rv.x), fmaf(beta, pv.y, rv.y),
            fmaf(beta, pv.z, rv.z), fmaf(beta, pv.w, rv.w));
    }
}

extern "C" void kernel_launch(void* const* d_in, const int* in_sizes, int n_in,
                              void* d_out, int out_size, void* d_ws, size_t ws_size,
                              hipStream_t stream)
{
    const float* img = (const float*)d_in[0];
    const float* k15 = (const float*)d_in[1];
    const float* rks = (const float*)d_in[2];
    const float* rw  = (const float*)d_in[3];

    float* out = (float*)d_out;
    float* xs = out;            // x slot
    float* rs = out + CHW;      // r slot
    float* ps = out + 2 * CHW;  // p slot (doubles as odd-parity p buffer)

    float* ws   = (float*)d_ws;
    float* buf0 = ws;               // p buffer (even parity)
    float* Ap   = buf0 + CHW;
    float* scal = Ap + CHW;         // [101 rtr2][100 ptap] each SCALSZ floats
    float* rtr2 = scal;
    float* ptap = scal + 101 * SCALSZ;

    hipMemsetAsync(scal, 0, (size_t)(101 + 100) * SCALSZ * sizeof(float), stream);

    const dim3 gc(W / 64, H / 32, C), bc(256);
    const dim3 ge(HW / 2048, 1, C);

    // prologue: r0 = K^T b - A(x0); p0 = r0 -> buf0; x = img; rtr2[0] = ||r0||^2
    fusedA_k<0><<<gc, bc, 0, stream>>>(img, nullptr, k15, rks, rw,
                                       nullptr, rs, buf0, xs,
                                       nullptr, nullptr, rtr2);

    for (int i = 0; i < 100; ++i) {
        float* pin  = (i & 1) ? buf0 : ps;   // p_{i-1}
        float* pcur = (i & 1) ? ps : buf0;   // p_i
        if (i == 0) {
            fusedA_k<1><<<gc, bc, 0, stream>>>(buf0, nullptr, k15, rks, rw,
                                               Ap, nullptr, nullptr, nullptr,
                                               nullptr, nullptr, ptap);
        } else {
            fusedA_k<2><<<gc, bc, 0, stream>>>(pin, rs, k15, rks, rw,
                                               Ap, nullptr, pcur, nullptr,
                                               rtr2 + i * SCALSZ, rtr2 + (i - 1) * SCALSZ,
                                               ptap + i * SCALSZ);
        }
        cg_update_k<<<ge, bc, 0, stream>>>(xs, rs, Ap, pcur,
                                           rtr2 + i * SCALSZ, ptap + i * SCALSZ,
                                           rtr2 + (i + 1) * SCALSZ);
    }
    // p_100 = r + beta_99 * p_99 ; p_99 is in ps
    p_final_k<<<ge, bc, 0, stream>>>(rs, ps, ps, rtr2 + 100 * SCALSZ, rtr2 + 99 * SCALSZ);
}

// Round 5
// 9897.107 us; speedup vs baseline: 1.0809x; 1.0809x over previous
//
#include <hip/hip_runtime.h>

#define EPS 1e-12f

constexpr int H = 768, W = 768, C = 3;
constexpr int HW = H * W;
constexpr int CHW = C * HW;

constexpr int NSLOT = 16;              // hashed atomic slots per scalar
constexpr int SSTR = 16;               // slot spacing (64B)
constexpr int SCALSZ = NSLOT * SSTR;

// LDS tile geometry (output tile 64x32, 256 threads, 8 px/thread)
constexpr int SPW = 100, SPH = 60;     // pe-tile: origin (-14,-14), 96 cols staged
constexpr int S0W = 84,  S0H = 46;     // t0-tile: origin (-7,-7), 80 cols written (78 valid)
constexpr int S1W = 76,  S1H = 36;     // t1/t2-tile: origin (-2,-2), 72 cols written (68 valid)
constexpr int UBUF = SPH * SPW;        // union buffer: pe then t0 (6000 >= 46*84)

__device__ __forceinline__ float block_reduce_256(float v, float* redbuf) {
    #pragma unroll
    for (int off = 32; off > 0; off >>= 1) v += __shfl_down(v, off, 64);
    const int tid = threadIdx.x;
    if ((tid & 63) == 0) redbuf[tid >> 6] = v;
    __syncthreads();
    return redbuf[0] + redbuf[1] + redbuf[2] + redbuf[3];
}

__device__ __forceinline__ float sum_slots(const float* base, int c) {
    float s = 0.f;
    #pragma unroll
    for (int k = 0; k < NSLOT; ++k) s += base[k * SSTR + c];
    return s;
}

// Precompute padded forward + flipped tap tables into ws:
// [0..239] k15 fwd (15 rows x 16), [240..479] k15 flipped,
// [480..559] rk fwd (2 x 5 rows x 8), [560..639] rk flipped
__global__ void tap_prep_k(const float* __restrict__ k15, const float* __restrict__ rks,
                           float* __restrict__ taps) {
    const int tid = threadIdx.x;
    if (tid < 240) {
        const int i = tid >> 4, j = tid & 15;
        taps[tid]       = (j < 15) ? k15[i * 15 + j] : 0.f;
        taps[240 + tid] = (j < 15) ? k15[(14 - i) * 15 + (14 - j)] : 0.f;
    }
    if (tid < 80) {
        const int kk = tid / 40, rem = tid % 40, i = rem >> 3, j = rem & 7;
        taps[480 + tid] = (j < 5) ? rks[kk * 25 + i * 5 + j] : 0.f;
        taps[560 + tid] = (j < 5) ? rks[kk * 25 + (4 - i) * 5 + (4 - j)] : 0.f;
    }
}

// Fused A-apply. MODE 0: prologue (in=img): r0 = corrT15(img) - A(img); outR,outP=r0, outX=img; red += ||r0||^2
// MODE 1: iter 0 (in=p0): Ap = A(p0); red += p.Ap
// MODE 2: iter>=1 (in=p_prev, rvec=r): pe = r + beta*p_prev (incl. halo); Ap = A(pe); pe->outP; red += pe.Ap
template <int MODE>
__global__ __launch_bounds__(256) void fusedA_k(
    const float* __restrict__ in, const float* __restrict__ rvec,
    const float* __restrict__ taps, const float* __restrict__ rw,
    float* __restrict__ Ap, float* __restrict__ outR,
    float* __restrict__ outP, float* __restrict__ outX,
    const float* __restrict__ bnum, const float* __restrict__ bden,
    float* __restrict__ red)
{
    __shared__ __align__(16) float ub[UBUF];        // pe tile, then reused for t0 tile
    __shared__ __align__(16) float st1[S1H * S1W];
    __shared__ __align__(16) float st2[S1H * S1W];
    __shared__ float redbuf[4];

    const float* kt   = taps;
    const float* ktf  = taps + 240;
    const float* rkt  = taps + 480;
    const float* rktf = taps + 560;

    const int c = blockIdx.z;
    const int bx = blockIdx.x * 64, by = blockIdx.y * 32;
    const int tid = threadIdx.x;
    const float* inC = in + c * HW;

    float beta = 0.f;
    if (MODE == 2) beta = sum_slots(bnum, c) / (sum_slots(bden, c) + EPS);

    // ---- stage pe tile (halo 14): 60 rows x 96 cols ----
    for (int t = tid; t < SPH * 96; t += 256) {
        const int ly = t / 96, lx = t - ly * 96;
        const int gy = by - 14 + ly, gx = bx - 14 + lx;
        float v = 0.f;
        if ((unsigned)gy < (unsigned)H && (unsigned)gx < (unsigned)W) {
            const int g = gy * W + gx;
            v = inC[g];
            if (MODE == 2) v = rvec[c * HW + g] + beta * v;
        }
        ub[ly * SPW + lx] = v;
    }
    __syncthreads();

    const int oy = tid >> 3;
    const int ox = (tid & 7) << 3;

    // ---- phase 1b: t1,t2 = corr5(pe) on 36 rows x 72 cols; write st1/st2 (no hazard with ub) ----
    {
        const int s0 = tid, s1 = tid + 256;
        const int row0 = s0 / 9, c0 = (s0 - row0 * 9) << 3;
        const int row1 = s1 / 9, c1 = (s1 - row1 * 9) << 3;
        const bool v1 = (s1 < 324);
        float b0[8], c0a[8], b1[8], c1a[8];
        #pragma unroll
        for (int k = 0; k < 8; ++k) { b0[k] = 0.f; c0a[k] = 0.f; b1[k] = 0.f; c1a[k] = 0.f; }

        float4 kb0 = *(const float4*)(rkt + 0), kb1 = *(const float4*)(rkt + 4);
        float4 kc0 = *(const float4*)(rkt + 40), kc1 = *(const float4*)(rkt + 44);
        #pragma unroll 1
        for (int i = 0; i < 5; ++i) {
            const int ip = (i < 4) ? i + 1 : 4;
            float4 nb0 = *(const float4*)(rkt + ip * 8),      nb1 = *(const float4*)(rkt + ip * 8 + 4);
            float4 nc0 = *(const float4*)(rkt + 40 + ip * 8), nc1 = *(const float4*)(rkt + 40 + ip * 8 + 4);
            float kb[8], kc[8];
            *(float4*)(kb) = kb0; *(float4*)(kb + 4) = kb1;
            *(float4*)(kc) = kc0; *(float4*)(kc + 4) = kc1;

            {
                const float* rp = ub + (row0 + 10 + i) * SPW + c0 + 8;
                float seg[16];
                #pragma unroll
                for (int q = 0; q < 4; ++q) *(float4*)(seg + 4 * q) = *(const float4*)(rp + 4 * q);
                #pragma unroll
                for (int j = 0; j < 5; ++j)
                    #pragma unroll
                    for (int k = 0; k < 8; ++k) {
                        b0[k]  = fmaf(seg[j + k + 2], kb[j], b0[k]);
                        c0a[k] = fmaf(seg[j + k + 2], kc[j], c0a[k]);
                    }
            }
            if (v1) {
                const float* rp = ub + (row1 + 10 + i) * SPW + c1 + 8;
                float seg[16];
                #pragma unroll
                for (int q = 0; q < 4; ++q) *(float4*)(seg + 4 * q) = *(const float4*)(rp + 4 * q);
                #pragma unroll
                for (int j = 0; j < 5; ++j)
                    #pragma unroll
                    for (int k = 0; k < 8; ++k) {
                        b1[k]  = fmaf(seg[j + k + 2], kb[j], b1[k]);
                        c1a[k] = fmaf(seg[j + k + 2], kc[j], c1a[k]);
                    }
            }
            kb0 = nb0; kb1 = nb1; kc0 = nc0; kc1 = nc1;
        }
        // zero outside image grid, then write
        {
            const int gy = by - 2 + row0, gxb = bx - 2 + c0;
            #pragma unroll
            for (int k = 0; k < 8; ++k) {
                const bool bad = ((unsigned)gy >= (unsigned)H) || ((unsigned)(gxb + k) >= (unsigned)W);
                if (bad) { b0[k] = 0.f; c0a[k] = 0.f; }
            }
            float* o1 = st1 + row0 * S1W + c0;
            float* o2 = st2 + row0 * S1W + c0;
            *(float4*)(o1)     = make_float4(b0[0], b0[1], b0[2], b0[3]);
            *(float4*)(o1 + 4) = make_float4(b0[4], b0[5], b0[6], b0[7]);
            *(float4*)(o2)     = make_float4(c0a[0], c0a[1], c0a[2], c0a[3]);
            *(float4*)(o2 + 4) = make_float4(c0a[4], c0a[5], c0a[6], c0a[7]);
        }
        if (v1) {
            const int gy = by - 2 + row1, gxb = bx - 2 + c1;
            #pragma unroll
            for (int k = 0; k < 8; ++k) {
                const bool bad = ((unsigned)gy >= (unsigned)H) || ((unsigned)(gxb + k) >= (unsigned)W);
                if (bad) { b1[k] = 0.f; c1a[k] = 0.f; }
            }
            float* o1 = st1 + row1 * S1W + c1;
            float* o2 = st2 + row1 * S1W + c1;
            *(float4*)(o1)     = make_float4(b1[0], b1[1], b1[2], b1[3]);
            *(float4*)(o1 + 4) = make_float4(b1[4], b1[5], b1[6], b1[7]);
            *(float4*)(o2)     = make_float4(c1a[0], c1a[1], c1a[2], c1a[3]);
            *(float4*)(o2 + 4) = make_float4(c1a[4], c1a[5], c1a[6], c1a[7]);
        }
    }

    // ---- stash pe center (epilogue needs it after ub is overwritten) ----
    float pctr[8];
    {
        const float* ctr = ub + (oy + 14) * SPW + ox + 14;
        #pragma unroll
        for (int k = 0; k < 8; ++k) pctr[k] = ctr[k];
    }

    // ---- MODE 0 only: vimg = corrT15(img) at center (reads pe tile) ----
    float vimg[8];
    if (MODE == 0) {
        #pragma unroll
        for (int k = 0; k < 8; ++k) vimg[k] = 0.f;
        #pragma unroll 1
        for (int i = 0; i < 15; ++i) {
            const float* rowp = ub + (oy + 7 + i) * SPW + ox + 4;
            float seg[28];
            #pragma unroll
            for (int q = 0; q < 7; ++q) *(float4*)(seg + 4 * q) = *(const float4*)(rowp + 4 * q);
            float kv[16];
            #pragma unroll
            for (int q = 0; q < 4; ++q) *(float4*)(kv + 4 * q) = *(const float4*)(ktf + i * 16 + 4 * q);
            #pragma unroll
            for (int j = 0; j < 15; ++j)
                #pragma unroll
                for (int k = 0; k < 8; ++k) vimg[k] = fmaf(seg[j + k + 3], kv[j], vimg[k]);
        }
    }

    // ---- phase 1a: t0 = corr15(pe) on 46 rows x 80 cols -> registers ----
    const int s0 = tid, s1 = tid + 256;
    const int row0 = s0 / 10, ca0 = (s0 - row0 * 10) << 3;
    const int row1 = s1 / 10, ca1 = (s1 - row1 * 10) << 3;
    const bool av1 = (s1 < 460);
    float a0[8], a1[8];
    #pragma unroll
    for (int k = 0; k < 8; ++k) { a0[k] = 0.f; a1[k] = 0.f; }
    {
        float4 k0 = *(const float4*)(kt + 0), k1 = *(const float4*)(kt + 4);
        float4 k2 = *(const float4*)(kt + 8), k3 = *(const float4*)(kt + 12);
        #pragma unroll 1
        for (int i = 0; i < 15; ++i) {
            const int ip = (i < 14) ? i + 1 : 14;
            float4 n0 = *(const float4*)(kt + ip * 16),     n1 = *(const float4*)(kt + ip * 16 + 4);
            float4 n2 = *(const float4*)(kt + ip * 16 + 8), n3 = *(const float4*)(kt + ip * 16 + 12);
            float kv[16];
            *(float4*)(kv) = k0; *(float4*)(kv + 4) = k1;
            *(float4*)(kv + 8) = k2; *(float4*)(kv + 12) = k3;
            {
                const float* rp = ub + (row0 + i) * SPW + ca0;
                float seg[24];
                #pragma unroll
                for (int q = 0; q < 6; ++q) *(float4*)(seg + 4 * q) = *(const float4*)(rp + 4 * q);
                #pragma unroll
                for (int j = 0; j < 15; ++j)
                    #pragma unroll
                    for (int k = 0; k < 8; ++k) a0[k] = fmaf(seg[j + k], kv[j], a0[k]);
            }
            if (av1) {
                const float* rp = ub + (row1 + i) * SPW + ca1;
                float seg[24];
                #pragma unroll
                for (int q = 0; q < 6; ++q) *(float4*)(seg + 4 * q) = *(const float4*)(rp + 4 * q);
                #pragma unroll
                for (int j = 0; j < 15; ++j)
                    #pragma unroll
                    for (int k = 0; k < 8; ++k) a1[k] = fmaf(seg[j + k], kv[j], a1[k]);
            }
            k0 = n0; k1 = n1; k2 = n2; k3 = n3;
        }
    }
    // zero outside image grid
    {
        const int gy = by - 7 + row0, gxb = bx - 7 + ca0;
        #pragma unroll
        for (int k = 0; k < 8; ++k)
            if (((unsigned)gy >= (unsigned)H) || ((unsigned)(gxb + k) >= (unsigned)W)) a0[k] = 0.f;
    }
    if (av1) {
        const int gy = by - 7 + row1, gxb = bx - 7 + ca1;
        #pragma unroll
        for (int k = 0; k < 8; ++k)
            if (((unsigned)gy >= (unsigned)H) || ((unsigned)(gxb + k) >= (unsigned)W)) a1[k] = 0.f;
    }

    __syncthreads();   // all reads of pe tile complete

    // ---- write t0 into ub (st0 layout) ----
    {
        float* o = ub + row0 * S0W + ca0;
        *(float4*)(o)     = make_float4(a0[0], a0[1], a0[2], a0[3]);
        *(float4*)(o + 4) = make_float4(a0[4], a0[5], a0[6], a0[7]);
    }
    if (av1) {
        float* o = ub + row1 * S0W + ca1;
        *(float4*)(o)     = make_float4(a1[0], a1[1], a1[2], a1[3]);
        *(float4*)(o + 4) = make_float4(a1[4], a1[5], a1[6], a1[7]);
    }
    __syncthreads();

    // ---- phase 2: adjoint convs -> 64x32 output tile ----
    float acc[8];
    #pragma unroll
    for (int k = 0; k < 8; ++k) acc[k] = 0.f;
    {
        float4 k0 = *(const float4*)(ktf + 0), k1 = *(const float4*)(ktf + 4);
        float4 k2 = *(const float4*)(ktf + 8), k3 = *(const float4*)(ktf + 12);
        #pragma unroll 1
        for (int i = 0; i < 15; ++i) {
            const int ip = (i < 14) ? i + 1 : 14;
            float4 n0 = *(const float4*)(ktf + ip * 16),     n1 = *(const float4*)(ktf + ip * 16 + 4);
            float4 n2 = *(const float4*)(ktf + ip * 16 + 8), n3 = *(const float4*)(ktf + ip * 16 + 12);
            float kv[16];
            *(float4*)(kv) = k0; *(float4*)(kv + 4) = k1;
            *(float4*)(kv + 8) = k2; *(float4*)(kv + 12) = k3;
            const float* rp = ub + (oy + i) * S0W + ox;
            float seg[24];
            #pragma unroll
            for (int q = 0; q < 6; ++q) *(float4*)(seg + 4 * q) = *(const float4*)(rp + 4 * q);
            #pragma unroll
            for (int j = 0; j < 15; ++j)
                #pragma unroll
                for (int k = 0; k < 8; ++k) acc[k] = fmaf(seg[j + k], kv[j], acc[k]);
            k0 = n0; k1 = n1; k2 = n2; k3 = n3;
        }
    }

    float accB[8], accC[8];
    #pragma unroll
    for (int k = 0; k < 8; ++k) { accB[k] = 0.f; accC[k] = 0.f; }
    {
        float4 kb0 = *(const float4*)(rktf + 0), kb1 = *(const float4*)(rktf + 4);
        float4 kc0 = *(const float4*)(rktf + 40), kc1 = *(const float4*)(rktf + 44);
        #pragma unroll 1
        for (int i = 0; i < 5; ++i) {
            const int ip = (i < 4) ? i + 1 : 4;
            float4 nb0 = *(const float4*)(rktf + ip * 8),      nb1 = *(const float4*)(rktf + ip * 8 + 4);
            float4 nc0 = *(const float4*)(rktf + 40 + ip * 8), nc1 = *(const float4*)(rktf + 40 + ip * 8 + 4);
            float kb[8], kc[8];
            *(float4*)(kb) = kb0; *(float4*)(kb + 4) = kb1;
            *(float4*)(kc) = kc0; *(float4*)(kc + 4) = kc1;
            const float* r1p = st1 + (oy + i) * S1W + ox;
            const float* r2p = st2 + (oy + i) * S1W + ox;
            float sA[12], sB[12];
            #pragma unroll
            for (int q = 0; q < 3; ++q) *(float4*)(sA + 4 * q) = *(const float4*)(r1p + 4 * q);
            #pragma unroll
            for (int q = 0; q < 3; ++q) *(float4*)(sB + 4 * q) = *(const float4*)(r2p + 4 * q);
            #pragma unroll
            for (int j = 0; j < 5; ++j)
                #pragma unroll
                for (int k = 0; k < 8; ++k) {
                    accB[k] = fmaf(sA[j + k], kb[j], accB[k]);
                    accC[k] = fmaf(sB[j + k], kc[j], accC[k]);
                }
            kb0 = nb0; kb1 = nb1; kc0 = nc0; kc1 = nc1;
        }
    }

    const float w0 = rw[0], w1 = rw[1];
    const float w02 = w0 * w0, w12 = w1 * w1;
    float v[8];
    #pragma unroll
    for (int k = 0; k < 8; ++k) v[k] = acc[k] + w02 * accB[k] + w12 * accC[k];

    const int g = c * HW + (by + oy) * W + bx + ox;
    float local = 0.f;
    if (MODE == 0) {
        #pragma unroll
        for (int k = 0; k < 8; ++k) v[k] = vimg[k] - v[k];
        *(float4*)(outR + g)     = make_float4(v[0], v[1], v[2], v[3]);
        *(float4*)(outR + g + 4) = make_float4(v[4], v[5], v[6], v[7]);
        *(float4*)(outP + g)     = make_float4(v[0], v[1], v[2], v[3]);
        *(float4*)(outP + g + 4) = make_float4(v[4], v[5], v[6], v[7]);
        *(float4*)(outX + g)     = make_float4(pctr[0], pctr[1], pctr[2], pctr[3]);
        *(float4*)(outX + g + 4) = make_float4(pctr[4], pctr[5], pctr[6], pctr[7]);
        #pragma unroll
        for (int k = 0; k < 8; ++k) local += v[k] * v[k];
    } else {
        *(float4*)(Ap + g)     = make_float4(v[0], v[1], v[2], v[3]);
        *(float4*)(Ap + g + 4) = make_float4(v[4], v[5], v[6], v[7]);
        #pragma unroll
        for (int k = 0; k < 8; ++k) local += pctr[k] * v[k];
        if (MODE == 2) {
            *(float4*)(outP + g)     = make_float4(pctr[0], pctr[1], pctr[2], pctr[3]);
            *(float4*)(outP + g + 4) = make_float4(pctr[4], pctr[5], pctr[6], pctr[7]);
        }
    }
    const float tot = block_reduce_256(local, redbuf);
    if (tid == 0) {
        const int bid = blockIdx.y * gridDim.x + blockIdx.x;
        atomicAdd(red + (bid & (NSLOT - 1)) * SSTR + c, tot);
    }
}

// x += alpha*p; r -= alpha*Ap; accumulate ||r_new||^2
__global__ __launch_bounds__(256) void cg_update_k(
    float* __restrict__ x, float* __restrict__ r,
    const float* __restrict__ Ap, const float* __restrict__ p,
    const float* __restrict__ rtr_cur, const float* __restrict__ ptap,
    float* __restrict__ rtr_next)
{
    __shared__ float redbuf[4];
    const int c = blockIdx.z;
    const float n = sum_slots(rtr_cur, c), d = sum_slots(ptap, c);
    const float alpha = n / (d + EPS);
    const int idx = c * HW + (blockIdx.x * 256 + threadIdx.x) * 8;
    float local = 0.f;
    #pragma unroll
    for (int h = 0; h < 2; ++h) {
        const int o = idx + 4 * h;
        float4 xv = *(float4*)(x + o);
        float4 rv = *(float4*)(r + o);
        const float4 pv = *(const float4*)(p + o);
        const float4 av = *(const float4*)(Ap + o);
        xv.x = fmaf(alpha, pv.x, xv.x); rv.x = fmaf(-alpha, av.x, rv.x);
        xv.y = fmaf(alpha, pv.y, xv.y); rv.y = fmaf(-alpha, av.y, rv.y);
        xv.z = fmaf(alpha, pv.z, xv.z); rv.z = fmaf(-alpha, av.z, rv.z);
        xv.w = fmaf(alpha, pv.w, xv.w); rv.w = fmaf(-alpha, av.w, rv.w);
        *(float4*)(x + o) = xv;
        *(float4*)(r + o) = rv;
        local += rv.x * rv.x + rv.y * rv.y + rv.z * rv.z + rv.w * rv.w;
    }
    const float tot = block_reduce_256(local, redbuf);
    if (threadIdx.x == 0)
        atomicAdd(rtr_next + ((int)blockIdx.x & (NSLOT - 1)) * SSTR + c, tot);
}

// final: p = r + beta*p99
__global__ __launch_bounds__(256) void p_final_k(
    const float* __restrict__ r, const float* __restrict__ p99, float* __restrict__ pout,
    const float* __restrict__ num, const float* __restrict__ den)
{
    const int c = blockIdx.z;
    const float beta = sum_slots(num, c) / (sum_slots(den, c) + EPS);
    const int idx = c * HW + (blockIdx.x * 256 + threadIdx.x) * 8;
    #pragma unroll
    for (int h = 0; h < 2; ++h) {
        const int o = idx + 4 * h;
        const float4 rv = *(const float4*)(r + o);
        const float4 pv = *(const float4*)(p99 + o);
        *(float4*)(pout + o) = make_float4(
            fmaf(beta, pv.x, rv.x), fmaf(beta, pv.y, rv.y),
            fmaf(beta, pv.z, rv.z), fmaf(beta, pv.w, rv.w));
    }
}

extern "C" void kernel_launch(void* const* d_in, const int* in_sizes, int n_in,
                              void* d_out, int out_size, void* d_ws, size_t ws_size,
                              hipStream_t stream)
{
    const float* img = (const float*)d_in[0];
    const float* k15 = (const float*)d_in[1];
    const float* rks = (const float*)d_in[2];
    const float* rw  = (const float*)d_in[3];

    float* out = (float*)d_out;
    float* xs = out;            // x slot
    float* rs = out + CHW;      // r slot
    float* ps = out + 2 * CHW;  // p slot (doubles as odd-parity p buffer)

    float* ws   = (float*)d_ws;
    float* buf0 = ws;               // p buffer (even parity)
    float* Ap   = buf0 + CHW;
    float* scal = Ap + CHW;         // [101 rtr2][100 ptap] each SCALSZ floats
    float* rtr2 = scal;
    float* ptap = scal + 101 * SCALSZ;
    float* taps = scal + 201 * SCALSZ;  // 640 floats of prepped taps

    hipMemsetAsync(scal, 0, (size_t)(101 + 100) * SCALSZ * sizeof(float), stream);
    tap_prep_k<<<1, 256, 0, stream>>>(k15, rks, taps);

    const dim3 gc(W / 64, H / 32, C), bc(256);
    const dim3 ge(HW / 2048, 1, C);

    // prologue: r0 = K^T b - A(x0); p0 = r0 -> buf0; x = img; rtr2[0] = ||r0||^2
    fusedA_k<0><<<gc, bc, 0, stream>>>(img, nullptr, taps, rw,
                                       nullptr, rs, buf0, xs,
                                       nullptr, nullptr, rtr2);

    for (int i = 0; i < 100; ++i) {
        float* pin  = (i & 1) ? buf0 : ps;   // p_{i-1}
        float* pcur = (i & 1) ? ps : buf0;   // p_i
        if (i == 0) {
            fusedA_k<1><<<gc, bc, 0, stream>>>(buf0, nullptr, taps, rw,
                                               Ap, nullptr, nullptr, nullptr,
                                               nullptr, nullptr, ptap);
        } else {
            fusedA_k<2><<<gc, bc, 0, stream>>>(pin, rs, taps, rw,
                                               Ap, nullptr, pcur, nullptr,
                                               rtr2 + i * SCALSZ, rtr2 + (i - 1) * SCALSZ,
                                               ptap + i * SCALSZ);
        }
        cg_update_k<<<ge, bc, 0, stream>>>(xs, rs, Ap, pcur,
                                           rtr2 + i * SCALSZ, ptap + i * SCALSZ,
                                           rtr2 + (i + 1) * SCALSZ);
    }
    // p_100 = r + beta_99 * p_99 ; p_99 is in ps
    p_final_k<<<ge, bc, 0, stream>>>(rs, ps, ps, rtr2 + 100 * SCALSZ, rtr2 + 99 * SCALSZ);
}

// Round 6
// 9706.008 us; speedup vs baseline: 1.1022x; 1.0197x over previous
//
#include <hip/hip_runtime.h>

#define EPS 1e-12f

constexpr int H = 768, W = 768, C = 3;
constexpr int HW = H * W;
constexpr int CHW = C * HW;

constexpr int NSLOT = 16;              // hashed atomic slots per scalar
constexpr int SSTR = 16;               // slot spacing (64B)
constexpr int SCALSZ = NSLOT * SSTR;

// ---- edge (two-pass) kernel geometry: 64x32 tile, round-5 proven ----
constexpr int SPW = 100, SPH = 60;
constexpr int S0W = 84,  S0H = 46;
constexpr int S1W = 76,  S1H = 36;
constexpr int UBUF = SPH * SPW;

// ---- interior (composed 29x29) kernel: 64x32 tile, patches 4w x 2t ----
constexpr int IPW = 92, IPH = 60;      // pe tile: 60 rows x 92 cols, halo 14

__device__ __forceinline__ float block_reduce_256(float v, float* redbuf) {
    #pragma unroll
    for (int off = 32; off > 0; off >>= 1) v += __shfl_down(v, off, 64);
    const int tid = threadIdx.x;
    if ((tid & 63) == 0) redbuf[tid >> 6] = v;
    __syncthreads();
    return redbuf[0] + redbuf[1] + redbuf[2] + redbuf[3];
}

__device__ __forceinline__ float sum_slots(const float* base, int c) {
    float s = 0.f;
    #pragma unroll
    for (int k = 0; k < NSLOT; ++k) s += base[k * SSTR + c];
    return s;
}

// taps layout: [0..239] k15 fwd (15x16), [240..479] k15 flipped,
// [480..559] rk fwd (2x5x8), [560..639] rk flipped, [640..1683] TK 29x36 composed
__global__ void tap_prep_k(const float* __restrict__ k15, const float* __restrict__ rks,
                           const float* __restrict__ rw, float* __restrict__ taps) {
    const int tid = threadIdx.x;
    if (tid < 240) {
        const int i = tid >> 4, j = tid & 15;
        taps[tid]       = (j < 15) ? k15[i * 15 + j] : 0.f;
        taps[240 + tid] = (j < 15) ? k15[(14 - i) * 15 + (14 - j)] : 0.f;
    }
    if (tid < 80) {
        const int kk = tid / 40, rem = tid % 40, i = rem >> 3, j = rem & 7;
        taps[480 + tid] = (j < 5) ? rks[kk * 25 + i * 5 + j] : 0.f;
        taps[560 + tid] = (j < 5) ? rks[kk * 25 + (4 - i) * 5 + (4 - j)] : 0.f;
    }
    const float w20 = rw[0] * rw[0], w21 = rw[1] * rw[1];
    for (int t = tid; t < 29 * 36; t += 256) {
        const int uy = t / 36, ux = t - uy * 36;
        float s = 0.f;
        if (ux < 29) {
            const int dy = uy - 14, dx = ux - 14;
            for (int sy = 0; sy < 15; ++sy) {
                const int ty = sy + dy;
                if ((unsigned)ty >= 15u) continue;
                for (int sx = 0; sx < 15; ++sx) {
                    const int tx = sx + dx;
                    if ((unsigned)tx < 15u) s += k15[sy * 15 + sx] * k15[ty * 15 + tx];
                }
            }
            if (dy >= -4 && dy <= 4 && dx >= -4 && dx <= 4) {
                float q0 = 0.f, q1 = 0.f;
                for (int sy = 0; sy < 5; ++sy) {
                    const int ty = sy + dy;
                    if ((unsigned)ty >= 5u) continue;
                    for (int sx = 0; sx < 5; ++sx) {
                        const int tx = sx + dx;
                        if ((unsigned)tx >= 5u) continue;
                        q0 += rks[sy * 5 + sx] * rks[ty * 5 + tx];
                        q1 += rks[25 + sy * 5 + sx] * rks[25 + ty * 5 + tx];
                    }
                }
                s += w20 * q0 + w21 * q1;
            }
        }
        taps[640 + t] = s;
    }
}

// Interior tiles: exact composed 29x29 correlation (valid because every output px is
// >=7 from the image edge -> the two-pass intermediate's support is fully in-grid).
// pe = rvec + beta*pprev (beta=0 path for iter 0 via zeroed slots, pprev=rvec).
template <bool WRITEP>
__global__ __launch_bounds__(256) void interiorA_k(
    const float* __restrict__ pprev, const float* __restrict__ rvec,
    const float* __restrict__ tk,
    float* __restrict__ Ap, float* __restrict__ outP,
    const float* __restrict__ bnum, const float* __restrict__ bden,
    float* __restrict__ red)
{
    __shared__ __align__(16) float pe[IPH * IPW];
    __shared__ float redbuf[4];
    const int c = blockIdx.z;
    const int bx = 64 + blockIdx.x * 64, by = 32 + blockIdx.y * 32;
    const int tid = threadIdx.x;
    const float beta = sum_slots(bnum, c) / (sum_slots(bden, c) + EPS);
    const float* pC = pprev + c * HW;
    const float* rC = rvec + c * HW;
    const int gy0 = by - 14, gx0 = bx - 14;

    // stage pe (fully in-grid, coalesced, no bounds checks)
    for (int t = tid; t < IPH * IPW; t += 256) {
        const int ly = t / IPW, lx = t - ly * IPW;
        const int g = (gy0 + ly) * W + gx0 + lx;
        pe[t] = fmaf(beta, pC[g], rC[g]);
    }
    __syncthreads();

    const int ox = (tid & 15) << 2;       // 0..60
    const int o0 = (tid >> 4) << 1;       // 0..30 (2 output rows)

    float a0[4], a1[4];
    #pragma unroll
    for (int k = 0; k < 4; ++k) { a0[k] = 0.f; a1[k] = 0.f; }

    // d = 0: tap row 0 -> a0 only
    {
        const float* rp = pe + o0 * IPW + ox;
        float seg[32];
        #pragma unroll
        for (int q = 0; q < 8; ++q) *(float4*)(seg + 4 * q) = *(const float4*)(rp + 4 * q);
        #pragma unroll
        for (int j = 0; j < 29; ++j) {
            const float kv = tk[j];
            #pragma unroll
            for (int k = 0; k < 4; ++k) a0[k] = fmaf(seg[j + k], kv, a0[k]);
        }
    }
    // d = 1..28: tap rows d (a0) and d-1 (a1)
    #pragma unroll 1
    for (int d = 1; d <= 28; ++d) {
        const float* rp = pe + (o0 + d) * IPW + ox;
        float seg[32];
        #pragma unroll
        for (int q = 0; q < 8; ++q) *(float4*)(seg + 4 * q) = *(const float4*)(rp + 4 * q);
        const float* kr0 = tk + d * 36;
        const float* kr1 = kr0 - 36;
        #pragma unroll
        for (int j = 0; j < 29; ++j) {
            const float kv0 = kr0[j], kv1 = kr1[j];
            #pragma unroll
            for (int k = 0; k < 4; ++k) {
                a0[k] = fmaf(seg[j + k], kv0, a0[k]);
                a1[k] = fmaf(seg[j + k], kv1, a1[k]);
            }
        }
    }
    // d = 29: tap row 28 -> a1 only
    {
        const float* rp = pe + (o0 + 29) * IPW + ox;
        float seg[32];
        #pragma unroll
        for (int q = 0; q < 8; ++q) *(float4*)(seg + 4 * q) = *(const float4*)(rp + 4 * q);
        const float* kr1 = tk + 28 * 36;
        #pragma unroll
        for (int j = 0; j < 29; ++j) {
            const float kv = kr1[j];
            #pragma unroll
            for (int k = 0; k < 4; ++k) a1[k] = fmaf(seg[j + k], kv, a1[k]);
        }
    }

    const int gbase = c * HW + (by + o0) * W + bx + ox;
    const float* c0p = pe + (o0 + 14) * IPW + ox + 14;
    const float* c1p = c0p + IPW;
    *(float4*)(Ap + gbase)     = make_float4(a0[0], a0[1], a0[2], a0[3]);
    *(float4*)(Ap + gbase + W) = make_float4(a1[0], a1[1], a1[2], a1[3]);
    float local = 0.f;
    #pragma unroll
    for (int k = 0; k < 4; ++k) local += c0p[k] * a0[k] + c1p[k] * a1[k];
    if (WRITEP) {
        *(float4*)(outP + gbase)     = make_float4(c0p[0], c0p[1], c0p[2], c0p[3]);
        *(float4*)(outP + gbase + W) = make_float4(c1p[0], c1p[1], c1p[2], c1p[3]);
    }
    const float tot = block_reduce_256(local, redbuf);
    if (tid == 0) {
        const int bid = blockIdx.y * gridDim.x + blockIdx.x;
        atomicAdd(red + (bid & (NSLOT - 1)) * SSTR + c, tot);
    }
}

// Edge / prologue kernel: round-5 two-pass fused A (exact boundary handling).
// REMAP=true: blockIdx.x indexes the 68 perimeter tiles of the 12x24 grid.
template <int MODE, bool REMAP>
__global__ __launch_bounds__(256) void fusedA_k(
    const float* __restrict__ in, const float* __restrict__ rvec,
    const float* __restrict__ taps, const float* __restrict__ rw,
    float* __restrict__ Ap, float* __restrict__ outR,
    float* __restrict__ outP, float* __restrict__ outX,
    const float* __restrict__ bnum, const float* __restrict__ bden,
    float* __restrict__ red)
{
    __shared__ __align__(16) float ub[UBUF];
    __shared__ __align__(16) float st1[S1H * S1W];
    __shared__ __align__(16) float st2[S1H * S1W];
    __shared__ float redbuf[4];

    const float* kt   = taps;
    const float* ktf  = taps + 240;
    const float* rkt  = taps + 480;
    const float* rktf = taps + 560;

    int tbx, tby;
    if (REMAP) {
        const int e = blockIdx.x;
        if (e < 12)      { tbx = e;      tby = 0; }
        else if (e < 24) { tbx = e - 12; tby = 23; }
        else if (e < 46) { tbx = 0;      tby = 1 + (e - 24); }
        else             { tbx = 11;     tby = 1 + (e - 46); }
    } else { tbx = blockIdx.x; tby = blockIdx.y; }

    const int c = blockIdx.z;
    const int bx = tbx * 64, by = tby * 32;
    const int tid = threadIdx.x;
    const float* inC = in + c * HW;

    float beta = 0.f;
    if (MODE == 2) beta = sum_slots(bnum, c) / (sum_slots(bden, c) + EPS);

    for (int t = tid; t < SPH * 96; t += 256) {
        const int ly = t / 96, lx = t - ly * 96;
        const int gy = by - 14 + ly, gx = bx - 14 + lx;
        float v = 0.f;
        if ((unsigned)gy < (unsigned)H && (unsigned)gx < (unsigned)W) {
            const int g = gy * W + gx;
            v = inC[g];
            if (MODE == 2) v = rvec[c * HW + g] + beta * v;
        }
        ub[ly * SPW + lx] = v;
    }
    __syncthreads();

    const int oy = tid >> 3;
    const int ox = (tid & 7) << 3;

    // phase 1b: t1,t2 = corr5(pe)
    {
        const int s0 = tid, s1 = tid + 256;
        const int row0 = s0 / 9, c0 = (s0 - row0 * 9) << 3;
        const int row1 = s1 / 9, c1 = (s1 - row1 * 9) << 3;
        const bool v1 = (s1 < 324);
        float b0[8], c0a[8], b1[8], c1a[8];
        #pragma unroll
        for (int k = 0; k < 8; ++k) { b0[k] = 0.f; c0a[k] = 0.f; b1[k] = 0.f; c1a[k] = 0.f; }

        float4 kb0 = *(const float4*)(rkt + 0), kb1 = *(const float4*)(rkt + 4);
        float4 kc0 = *(const float4*)(rkt + 40), kc1 = *(const float4*)(rkt + 44);
        #pragma unroll 1
        for (int i = 0; i < 5; ++i) {
            const int ip = (i < 4) ? i + 1 : 4;
            float4 nb0 = *(const float4*)(rkt + ip * 8),      nb1 = *(const float4*)(rkt + ip * 8 + 4);
            float4 nc0 = *(const float4*)(rkt + 40 + ip * 8), nc1 = *(const float4*)(rkt + 40 + ip * 8 + 4);
            float kb[8], kc[8];
            *(float4*)(kb) = kb0; *(float4*)(kb + 4) = kb1;
            *(float4*)(kc) = kc0; *(float4*)(kc + 4) = kc1;
            {
                const float* rp = ub + (row0 + 10 + i) * SPW + c0 + 8;
                float seg[16];
                #pragma unroll
                for (int q = 0; q < 4; ++q) *(float4*)(seg + 4 * q) = *(const float4*)(rp + 4 * q);
                #pragma unroll
                for (int j = 0; j < 5; ++j)
                    #pragma unroll
                    for (int k = 0; k < 8; ++k) {
                        b0[k]  = fmaf(seg[j + k + 2], kb[j], b0[k]);
                        c0a[k] = fmaf(seg[j + k + 2], kc[j], c0a[k]);
                    }
            }
            if (v1) {
                const float* rp = ub + (row1 + 10 + i) * SPW + c1 + 8;
                float seg[16];
                #pragma unroll
                for (int q = 0; q < 4; ++q) *(float4*)(seg + 4 * q) = *(const float4*)(rp + 4 * q);
                #pragma unroll
                for (int j = 0; j < 5; ++j)
                    #pragma unroll
                    for (int k = 0; k < 8; ++k) {
                        b1[k]  = fmaf(seg[j + k + 2], kb[j], b1[k]);
                        c1a[k] = fmaf(seg[j + k + 2], kc[j], c1a[k]);
                    }
            }
            kb0 = nb0; kb1 = nb1; kc0 = nc0; kc1 = nc1;
        }
        {
            const int gy = by - 2 + row0, gxb = bx - 2 + c0;
            #pragma unroll
            for (int k = 0; k < 8; ++k) {
                const bool bad = ((unsigned)gy >= (unsigned)H) || ((unsigned)(gxb + k) >= (unsigned)W);
                if (bad) { b0[k] = 0.f; c0a[k] = 0.f; }
            }
            float* o1 = st1 + row0 * S1W + c0;
            float* o2 = st2 + row0 * S1W + c0;
            *(float4*)(o1)     = make_float4(b0[0], b0[1], b0[2], b0[3]);
            *(float4*)(o1 + 4) = make_float4(b0[4], b0[5], b0[6], b0[7]);
            *(float4*)(o2)     = make_float4(c0a[0], c0a[1], c0a[2], c0a[3]);
            *(float4*)(o2 + 4) = make_float4(c0a[4], c0a[5], c0a[6], c0a[7]);
        }
        if (v1) {
            const int gy = by - 2 + row1, gxb = bx - 2 + c1;
            #pragma unroll
            for (int k = 0; k < 8; ++k) {
                const bool bad = ((unsigned)gy >= (unsigned)H) || ((unsigned)(gxb + k) >= (unsigned)W);
                if (bad) { b1[k] = 0.f; c1a[k] = 0.f; }
            }
            float* o1 = st1 + row1 * S1W + c1;
            float* o2 = st2 + row1 * S1W + c1;
            *(float4*)(o1)     = make_float4(b1[0], b1[1], b1[2], b1[3]);
            *(float4*)(o1 + 4) = make_float4(b1[4], b1[5], b1[6], b1[7]);
            *(float4*)(o2)     = make_float4(c1a[0], c1a[1], c1a[2], c1a[3]);
            *(float4*)(o2 + 4) = make_float4(c1a[4], c1a[5], c1a[6], c1a[7]);
        }
    }

    float pctr[8];
    {
        const float* ctr = ub + (oy + 14) * SPW + ox + 14;
        #pragma unroll
        for (int k = 0; k < 8; ++k) pctr[k] = ctr[k];
    }

    float vimg[8];
    if (MODE == 0) {
        #pragma unroll
        for (int k = 0; k < 8; ++k) vimg[k] = 0.f;
        #pragma unroll 1
        for (int i = 0; i < 15; ++i) {
            const float* rowp = ub + (oy + 7 + i) * SPW + ox + 4;
            float seg[28];
            #pragma unroll
            for (int q = 0; q < 7; ++q) *(float4*)(seg + 4 * q) = *(const float4*)(rowp + 4 * q);
            float kv[16];
            #pragma unroll
            for (int q = 0; q < 4; ++q) *(float4*)(kv + 4 * q) = *(const float4*)(ktf + i * 16 + 4 * q);
            #pragma unroll
            for (int j = 0; j < 15; ++j)
                #pragma unroll
                for (int k = 0; k < 8; ++k) vimg[k] = fmaf(seg[j + k + 3], kv[j], vimg[k]);
        }
    }

    // phase 1a: t0 = corr15(pe) -> registers
    const int s0 = tid, s1 = tid + 256;
    const int row0 = s0 / 10, ca0 = (s0 - row0 * 10) << 3;
    const int row1 = s1 / 10, ca1 = (s1 - row1 * 10) << 3;
    const bool av1 = (s1 < 460);
    float a0[8], a1[8];
    #pragma unroll
    for (int k = 0; k < 8; ++k) { a0[k] = 0.f; a1[k] = 0.f; }
    {
        float4 k0 = *(const float4*)(kt + 0), k1 = *(const float4*)(kt + 4);
        float4 k2 = *(const float4*)(kt + 8), k3 = *(const float4*)(kt + 12);
        #pragma unroll 1
        for (int i = 0; i < 15; ++i) {
            const int ip = (i < 14) ? i + 1 : 14;
            float4 n0 = *(const float4*)(kt + ip * 16),     n1 = *(const float4*)(kt + ip * 16 + 4);
            float4 n2 = *(const float4*)(kt + ip * 16 + 8), n3 = *(const float4*)(kt + ip * 16 + 12);
            float kv[16];
            *(float4*)(kv) = k0; *(float4*)(kv + 4) = k1;
            *(float4*)(kv + 8) = k2; *(float4*)(kv + 12) = k3;
            {
                const float* rp = ub + (row0 + i) * SPW + ca0;
                float seg[24];
                #pragma unroll
                for (int q = 0; q < 6; ++q) *(float4*)(seg + 4 * q) = *(const float4*)(rp + 4 * q);
                #pragma unroll
                for (int j = 0; j < 15; ++j)
                    #pragma unroll
                    for (int k = 0; k < 8; ++k) a0[k] = fmaf(seg[j + k], kv[j], a0[k]);
            }
            if (av1) {
                const float* rp = ub + (row1 + i) * SPW + ca1;
                float seg[24];
                #pragma unroll
                for (int q = 0; q < 6; ++q) *(float4*)(seg + 4 * q) = *(const float4*)(rp + 4 * q);
                #pragma unroll
                for (int j = 0; j < 15; ++j)
                    #pragma unroll
                    for (int k = 0; k < 8; ++k) a1[k] = fmaf(seg[j + k], kv[j], a1[k]);
            }
            k0 = n0; k1 = n1; k2 = n2; k3 = n3;
        }
    }
    {
        const int gy = by - 7 + row0, gxb = bx - 7 + ca0;
        #pragma unroll
        for (int k = 0; k < 8; ++k)
            if (((unsigned)gy >= (unsigned)H) || ((unsigned)(gxb + k) >= (unsigned)W)) a0[k] = 0.f;
    }
    if (av1) {
        const int gy = by - 7 + row1, gxb = bx - 7 + ca1;
        #pragma unroll
        for (int k = 0; k < 8; ++k)
            if (((unsigned)gy >= (unsigned)H) || ((unsigned)(gxb + k) >= (unsigned)W)) a1[k] = 0.f;
    }

    __syncthreads();

    {
        float* o = ub + row0 * S0W + ca0;
        *(float4*)(o)     = make_float4(a0[0], a0[1], a0[2], a0[3]);
        *(float4*)(o + 4) = make_float4(a0[4], a0[5], a0[6], a0[7]);
    }
    if (av1) {
        float* o = ub + row1 * S0W + ca1;
        *(float4*)(o)     = make_float4(a1[0], a1[1], a1[2], a1[3]);
        *(float4*)(o + 4) = make_float4(a1[4], a1[5], a1[6], a1[7]);
    }
    __syncthreads();

    // phase 2: adjoint convs
    float acc[8];
    #pragma unroll
    for (int k = 0; k < 8; ++k) acc[k] = 0.f;
    {
        float4 k0 = *(const float4*)(ktf + 0), k1 = *(const float4*)(ktf + 4);
        float4 k2 = *(const float4*)(ktf + 8), k3 = *(const float4*)(ktf + 12);
        #pragma unroll 1
        for (int i = 0; i < 15; ++i) {
            const int ip = (i < 14) ? i + 1 : 14;
            float4 n0 = *(const float4*)(ktf + ip * 16),     n1 = *(const float4*)(ktf + ip * 16 + 4);
            float4 n2 = *(const float4*)(ktf + ip * 16 + 8), n3 = *(const float4*)(ktf + ip * 16 + 12);
            float kv[16];
            *(float4*)(kv) = k0; *(float4*)(kv + 4) = k1;
            *(float4*)(kv + 8) = k2; *(float4*)(kv + 12) = k3;
            const float* rp = ub + (oy + i) * S0W + ox;
            float seg[24];
            #pragma unroll
            for (int q = 0; q < 6; ++q) *(float4*)(seg + 4 * q) = *(const float4*)(rp + 4 * q);
            #pragma unroll
            for (int j = 0; j < 15; ++j)
                #pragma unroll
                for (int k = 0; k < 8; ++k) acc[k] = fmaf(seg[j + k], kv[j], acc[k]);
            k0 = n0; k1 = n1; k2 = n2; k3 = n3;
        }
    }

    float accB[8], accC[8];
    #pragma unroll
    for (int k = 0; k < 8; ++k) { accB[k] = 0.f; accC[k] = 0.f; }
    {
        float4 kb0 = *(const float4*)(rktf + 0), kb1 = *(const float4*)(rktf + 4);
        float4 kc0 = *(const float4*)(rktf + 40), kc1 = *(const float4*)(rktf + 44);
        #pragma unroll 1
        for (int i = 0; i < 5; ++i) {
            const int ip = (i < 4) ? i + 1 : 4;
            float4 nb0 = *(const float4*)(rktf + ip * 8),      nb1 = *(const float4*)(rktf + ip * 8 + 4);
            float4 nc0 = *(const float4*)(rktf + 40 + ip * 8), nc1 = *(const float4*)(rktf + 40 + ip * 8 + 4);
            float kb[8], kc[8];
            *(float4*)(kb) = kb0; *(float4*)(kb + 4) = kb1;
            *(float4*)(kc) = kc0; *(float4*)(kc + 4) = kc1;
            const float* r1p = st1 + (oy + i) * S1W + ox;
            const float* r2p = st2 + (oy + i) * S1W + ox;
            float sA[12], sB[12];
            #pragma unroll
            for (int q = 0; q < 3; ++q) *(float4*)(sA + 4 * q) = *(const float4*)(r1p + 4 * q);
            #pragma unroll
            for (int q = 0; q < 3; ++q) *(float4*)(sB + 4 * q) = *(const float4*)(r2p + 4 * q);
            #pragma unroll
            for (int j = 0; j < 5; ++j)
                #pragma unroll
                for (int k = 0; k < 8; ++k) {
                    accB[k] = fmaf(sA[j + k], kb[j], accB[k]);
                    accC[k] = fmaf(sB[j + k], kc[j], accC[k]);
                }
            kb0 = nb0; kb1 = nb1; kc0 = nc0; kc1 = nc1;
        }
    }

    const float w0 = rw[0], w1 = rw[1];
    const float w02 = w0 * w0, w12 = w1 * w1;
    float v[8];
    #pragma unroll
    for (int k = 0; k < 8; ++k) v[k] = acc[k] + w02 * accB[k] + w12 * accC[k];

    const int g = c * HW + (by + oy) * W + bx + ox;
    float local = 0.f;
    if (MODE == 0) {
        #pragma unroll
        for (int k = 0; k < 8; ++k) v[k] = vimg[k] - v[k];
        *(float4*)(outR + g)     = make_float4(v[0], v[1], v[2], v[3]);
        *(float4*)(outR + g + 4) = make_float4(v[4], v[5], v[6], v[7]);
        *(float4*)(outP + g)     = make_float4(v[0], v[1], v[2], v[3]);
        *(float4*)(outP + g + 4) = make_float4(v[4], v[5], v[6], v[7]);
        *(float4*)(outX + g)     = make_float4(pctr[0], pctr[1], pctr[2], pctr[3]);
        *(float4*)(outX + g + 4) = make_float4(pctr[4], pctr[5], pctr[6], pctr[7]);
        #pragma unroll
        for (int k = 0; k < 8; ++k) local += v[k] * v[k];
    } else {
        *(float4*)(Ap + g)     = make_float4(v[0], v[1], v[2], v[3]);
        *(float4*)(Ap + g + 4) = make_float4(v[4], v[5], v[6], v[7]);
        #pragma unroll
        for (int k = 0; k < 8; ++k) local += pctr[k] * v[k];
        if (MODE == 2) {
            *(float4*)(outP + g)     = make_float4(pctr[0], pctr[1], pctr[2], pctr[3]);
            *(float4*)(outP + g + 4) = make_float4(pctr[4], pctr[5], pctr[6], pctr[7]);
        }
    }
    const float tot = block_reduce_256(local, redbuf);
    if (tid == 0) {
        const int bid = REMAP ? (int)blockIdx.x : (int)(blockIdx.y * gridDim.x + blockIdx.x);
        atomicAdd(red + (bid & (NSLOT - 1)) * SSTR + c, tot);
    }
}

// x += alpha*p; r -= alpha*Ap; accumulate ||r_new||^2
__global__ __launch_bounds__(256) void cg_update_k(
    float* __restrict__ x, float* __restrict__ r,
    const float* __restrict__ Ap, const float* __restrict__ p,
    const float* __restrict__ rtr_cur, const float* __restrict__ ptap,
    float* __restrict__ rtr_next)
{
    __shared__ float redbuf[4];
    const int c = blockIdx.z;
    const float n = sum_slots(rtr_cur, c), d = sum_slots(ptap, c);
    const float alpha = n / (d + EPS);
    const int idx = c * HW + (blockIdx.x * 256 + threadIdx.x) * 8;
    float local = 0.f;
    #pragma unroll
    for (int h = 0; h < 2; ++h) {
        const int o = idx + 4 * h;
        float4 xv = *(float4*)(x + o);
        float4 rv = *(float4*)(r + o);
        const float4 pv = *(const float4*)(p + o);
        const float4 av = *(const float4*)(Ap + o);
        xv.x = fmaf(alpha, pv.x, xv.x); rv.x = fmaf(-alpha, av.x, rv.x);
        xv.y = fmaf(alpha, pv.y, xv.y); rv.y = fmaf(-alpha, av.y, rv.y);
        xv.z = fmaf(alpha, pv.z, xv.z); rv.z = fmaf(-alpha, av.z, rv.z);
        xv.w = fmaf(alpha, pv.w, xv.w); rv.w = fmaf(-alpha, av.w, rv.w);
        *(float4*)(x + o) = xv;
        *(float4*)(r + o) = rv;
        local += rv.x * rv.x + rv.y * rv.y + rv.z * rv.z + rv.w * rv.w;
    }
    const float tot = block_reduce_256(local, redbuf);
    if (threadIdx.x == 0)
        atomicAdd(rtr_next + ((int)blockIdx.x & (NSLOT - 1)) * SSTR + c, tot);
}

// final: p = r + beta*p99
__global__ __launch_bounds__(256) void p_final_k(
    const float* __restrict__ r, const float* __restrict__ p99, float* __restrict__ pout,
    const float* __restrict__ num, const float* __restrict__ den)
{
    const int c = blockIdx.z;
    const float beta = sum_slots(num, c) / (sum_slots(den, c) + EPS);
    const int idx = c * HW + (blockIdx.x * 256 + threadIdx.x) * 8;
    #pragma unroll
    for (int h = 0; h < 2; ++h) {
        const int o = idx + 4 * h;
        const float4 rv = *(const float4*)(r + o);
        const float4 pv = *(const float4*)(p99 + o);
        *(float4*)(pout + o) = make_float4(
            fmaf(beta, pv.x, rv.x), fmaf(beta, pv.y, rv.y),
            fmaf(beta, pv.z, rv.z), fmaf(beta, pv.w, rv.w));
    }
}

extern "C" void kernel_launch(void* const* d_in, const int* in_sizes, int n_in,
                              void* d_out, int out_size, void* d_ws, size_t ws_size,
                              hipStream_t stream)
{
    const float* img = (const float*)d_in[0];
    const float* k15 = (const float*)d_in[1];
    const float* rks = (const float*)d_in[2];
    const float* rw  = (const float*)d_in[3];

    float* out = (float*)d_out;
    float* xs = out;            // x slot
    float* rs = out + CHW;      // r slot
    float* ps = out + 2 * CHW;  // p slot (doubles as odd-parity p buffer)

    float* ws   = (float*)d_ws;
    float* buf0 = ws;               // p buffer (even parity)
    float* Ap   = buf0 + CHW;
    float* scal = Ap + CHW;         // [101 rtr2][100 ptap][1 zslot] each SCALSZ floats
    float* rtr2 = scal;
    float* ptap = scal + 101 * SCALSZ;
    float* zslot = scal + 201 * SCALSZ;
    float* taps = scal + 202 * SCALSZ;  // 1684 floats of prepped taps

    hipMemsetAsync(scal, 0, (size_t)202 * SCALSZ * sizeof(float), stream);
    tap_prep_k<<<1, 256, 0, stream>>>(k15, rks, rw, taps);
    const float* tk = taps + 640;

    const dim3 gfull(12, 24, 3), bc(256);
    const dim3 gint(10, 22, 3), gedge(68, 1, 3);
    const dim3 ge(HW / 2048, 1, C);

    // prologue: r0 = K^T b - A(x0); p0 = r0 -> buf0; x = img; rtr2[0] = ||r0||^2
    fusedA_k<0, false><<<gfull, bc, 0, stream>>>(img, nullptr, taps, rw,
                                                 nullptr, rs, buf0, xs,
                                                 nullptr, nullptr, rtr2);

    for (int i = 0; i < 100; ++i) {
        float* pin  = (i & 1) ? buf0 : ps;   // p_{i-1}
        float* pcur = (i & 1) ? ps : buf0;   // p_i
        if (i == 0) {
            // beta = 0 via zeroed slots; pe = buf0
            interiorA_k<false><<<gint, bc, 0, stream>>>(buf0, buf0, tk,
                                                        Ap, nullptr, zslot, zslot, ptap);
            fusedA_k<1, true><<<gedge, bc, 0, stream>>>(buf0, nullptr, taps, rw,
                                                        Ap, nullptr, nullptr, nullptr,
                                                        nullptr, nullptr, ptap);
        } else {
            interiorA_k<true><<<gint, bc, 0, stream>>>(pin, rs, tk,
                                                       Ap, pcur,
                                                       rtr2 + i * SCALSZ, rtr2 + (i - 1) * SCALSZ,
                                                       ptap + i * SCALSZ);
            fusedA_k<2, true><<<gedge, bc, 0, stream>>>(pin, rs, taps, rw,
                                                        Ap, nullptr, pcur, nullptr,
                                                        rtr2 + i * SCALSZ, rtr2 + (i - 1) * SCALSZ,
                                                        ptap + i * SCALSZ);
        }
        cg_update_k<<<ge, bc, 0, stream>>>(xs, rs, Ap, pcur,
                                           rtr2 + i * SCALSZ, ptap + i * SCALSZ,
                                           rtr2 + (i + 1) * SCALSZ);
    }
    // p_100 = r + beta_99 * p_99 ; p_99 is in ps
    p_final_k<<<ge, bc, 0, stream>>>(rs, ps, ps, rtr2 + 100 * SCALSZ, rtr2 + 99 * SCALSZ);
}

// Round 8
// 8743.961 us; speedup vs baseline: 1.2234x; 1.1100x over previous
//
#include <hip/hip_runtime.h>

#define EPS 1e-12f

constexpr int H = 768, W = 768, C = 3;
constexpr int HW = H * W;
constexpr int CHW = C * HW;

constexpr int NSLOT = 16;
constexpr int SSTR = 16;
constexpr int SCALSZ = NSLOT * SSTR;

// edge (two-pass) geometry
constexpr int SPW = 100, SPH = 60;
constexpr int S0W = 84;
constexpr int S1W = 76, S1H = 36;
constexpr int UBUF = SPH * SPW;              // 6000
constexpr int LDSE = UBUF + 2 * S1H * S1W;   // 8592 floats = 34.4 KB
// interior (composed 29x29) geometry
constexpr int IPW = 92, IPH = 60;

__device__ __forceinline__ float block_reduce_256(float v, float* redbuf) {
    #pragma unroll
    for (int off = 32; off > 0; off >>= 1) v += __shfl_down(v, off, 64);
    const int tid = threadIdx.x;
    if ((tid & 63) == 0) redbuf[tid >> 6] = v;
    __syncthreads();
    return redbuf[0] + redbuf[1] + redbuf[2] + redbuf[3];
}

__device__ __forceinline__ float sum_slots(const float* base, int c) {
    float s = 0.f;
    #pragma unroll
    for (int k = 0; k < NSLOT; ++k) s += base[k * SSTR + c];
    return s;
}

// taps: [0..239] k15 fwd (15x16), [240..479] k15 flip, [480..559] rk fwd (2x5x8),
// [560..639] rk flip, [640..1683] TK 29x36 composed, [1684] w0^2, [1685] w1^2
__global__ void tap_prep_k(const float* __restrict__ k15, const float* __restrict__ rks,
                           const float* __restrict__ rw, float* __restrict__ taps) {
    const int tid = threadIdx.x;
    if (tid < 240) {
        const int i = tid >> 4, j = tid & 15;
        taps[tid]       = (j < 15) ? k15[i * 15 + j] : 0.f;
        taps[240 + tid] = (j < 15) ? k15[(14 - i) * 15 + (14 - j)] : 0.f;
    }
    if (tid < 80) {
        const int kk = tid / 40, rem = tid % 40, i = rem >> 3, j = rem & 7;
        taps[480 + tid] = (j < 5) ? rks[kk * 25 + i * 5 + j] : 0.f;
        taps[560 + tid] = (j < 5) ? rks[kk * 25 + (4 - i) * 5 + (4 - j)] : 0.f;
    }
    const float w20 = rw[0] * rw[0], w21 = rw[1] * rw[1];
    if (tid == 0) { taps[1684] = w20; taps[1685] = w21; }
    for (int t = tid; t < 29 * 36; t += 256) {
        const int uy = t / 36, ux = t - uy * 36;
        float s = 0.f;
        if (ux < 29) {
            const int dy = uy - 14, dx = ux - 14;
            for (int sy = 0; sy < 15; ++sy) {
                const int ty = sy + dy;
                if ((unsigned)ty >= 15u) continue;
                for (int sx = 0; sx < 15; ++sx) {
                    const int tx = sx + dx;
                    if ((unsigned)tx < 15u) s += k15[sy * 15 + sx] * k15[ty * 15 + tx];
                }
            }
            if (dy >= -4 && dy <= 4 && dx >= -4 && dx <= 4) {
                float q0 = 0.f, q1 = 0.f;
                for (int sy = 0; sy < 5; ++sy) {
                    const int ty = sy + dy;
                    if ((unsigned)ty >= 5u) continue;
                    for (int sx = 0; sx < 5; ++sx) {
                        const int tx = sx + dx;
                        if ((unsigned)tx >= 5u) continue;
                        q0 += rks[sy * 5 + sx] * rks[ty * 5 + tx];
                        q1 += rks[25 + sy * 5 + sx] * rks[25 + ty * 5 + tx];
                    }
                }
                s += w20 * q0 + w21 * q1;
            }
        }
        taps[640 + t] = s;
    }
}

// ---------------- prologue: r0 = K^T b - A(img); p0 = r0; x0 = img; rtr0 ----------------
__global__ __launch_bounds__(256) void prologue_k(
    const float* __restrict__ img, const float* __restrict__ taps,
    float* __restrict__ outR, float* __restrict__ outP, float* __restrict__ outX,
    float* __restrict__ red)
{
    __shared__ __align__(16) float ub[UBUF];
    __shared__ __align__(16) float st1[S1H * S1W];
    __shared__ __align__(16) float st2[S1H * S1W];
    __shared__ float redbuf[4];

    const float* kt   = taps;
    const float* ktf  = taps + 240;
    const float* rkt  = taps + 480;
    const float* rktf = taps + 560;
    const float w02 = taps[1684], w12 = taps[1685];

    const int c = blockIdx.z;
    const int bx = blockIdx.x * 64, by = blockIdx.y * 32;
    const int tid = threadIdx.x;
    const float* inC = img + c * HW;

    for (int t = tid; t < SPH * 96; t += 256) {
        const int ly = t / 96, lx = t - ly * 96;
        const int gy = by - 14 + ly, gx = bx - 14 + lx;
        float v = 0.f;
        if ((unsigned)gy < (unsigned)H && (unsigned)gx < (unsigned)W) v = inC[gy * W + gx];
        ub[ly * SPW + lx] = v;
    }
    __syncthreads();

    const int oy = tid >> 3;
    const int ox = (tid & 7) << 3;

    // phase 1b: t1,t2 = corr5(img)
    {
        const int s0 = tid, s1i = tid + 256;
        const int row0 = s0 / 9, c0 = (s0 - row0 * 9) << 3;
        const int row1 = s1i / 9, c1 = (s1i - row1 * 9) << 3;
        const bool v1 = (s1i < 324);
        float b0[8], c0a[8], b1[8], c1a[8];
        #pragma unroll
        for (int k = 0; k < 8; ++k) { b0[k] = 0.f; c0a[k] = 0.f; b1[k] = 0.f; c1a[k] = 0.f; }
        #pragma unroll 1
        for (int i = 0; i < 5; ++i) {
            float kb[8], kc[8];
            #pragma unroll
            for (int q = 0; q < 2; ++q) {
                *(float4*)(kb + 4 * q) = *(const float4*)(rkt + i * 8 + 4 * q);
                *(float4*)(kc + 4 * q) = *(const float4*)(rkt + 40 + i * 8 + 4 * q);
            }
            {
                const float* rp = ub + (row0 + 10 + i) * SPW + c0 + 8;
                float seg[16];
                #pragma unroll
                for (int q = 0; q < 4; ++q) *(float4*)(seg + 4 * q) = *(const float4*)(rp + 4 * q);
                #pragma unroll
                for (int j = 0; j < 5; ++j)
                    #pragma unroll
                    for (int k = 0; k < 8; ++k) {
                        b0[k]  = fmaf(seg[j + k + 2], kb[j], b0[k]);
                        c0a[k] = fmaf(seg[j + k + 2], kc[j], c0a[k]);
                    }
            }
            if (v1) {
                const float* rp = ub + (row1 + 10 + i) * SPW + c1 + 8;
                float seg[16];
                #pragma unroll
                for (int q = 0; q < 4; ++q) *(float4*)(seg + 4 * q) = *(const float4*)(rp + 4 * q);
                #pragma unroll
                for (int j = 0; j < 5; ++j)
                    #pragma unroll
                    for (int k = 0; k < 8; ++k) {
                        b1[k]  = fmaf(seg[j + k + 2], kb[j], b1[k]);
                        c1a[k] = fmaf(seg[j + k + 2], kc[j], c1a[k]);
                    }
            }
        }
        {
            const int gy = by - 2 + row0, gxb = bx - 2 + c0;
            #pragma unroll
            for (int k = 0; k < 8; ++k)
                if (((unsigned)gy >= (unsigned)H) || ((unsigned)(gxb + k) >= (unsigned)W)) { b0[k] = 0.f; c0a[k] = 0.f; }
            float* o1 = st1 + row0 * S1W + c0;
            float* o2 = st2 + row0 * S1W + c0;
            *(float4*)(o1) = make_float4(b0[0], b0[1], b0[2], b0[3]);
            *(float4*)(o1 + 4) = make_float4(b0[4], b0[5], b0[6], b0[7]);
            *(float4*)(o2) = make_float4(c0a[0], c0a[1], c0a[2], c0a[3]);
            *(float4*)(o2 + 4) = make_float4(c0a[4], c0a[5], c0a[6], c0a[7]);
        }
        if (v1) {
            const int gy = by - 2 + row1, gxb = bx - 2 + c1;
            #pragma unroll
            for (int k = 0; k < 8; ++k)
                if (((unsigned)gy >= (unsigned)H) || ((unsigned)(gxb + k) >= (unsigned)W)) { b1[k] = 0.f; c1a[k] = 0.f; }
            float* o1 = st1 + row1 * S1W + c1;
            float* o2 = st2 + row1 * S1W + c1;
            *(float4*)(o1) = make_float4(b1[0], b1[1], b1[2], b1[3]);
            *(float4*)(o1 + 4) = make_float4(b1[4], b1[5], b1[6], b1[7]);
            *(float4*)(o2) = make_float4(c1a[0], c1a[1], c1a[2], c1a[3]);
            *(float4*)(o2 + 4) = make_float4(c1a[4], c1a[5], c1a[6], c1a[7]);
        }
    }

    float pctr[8];
    {
        const float* ctr = ub + (oy + 14) * SPW + ox + 14;
        #pragma unroll
        for (int k = 0; k < 8; ++k) pctr[k] = ctr[k];
    }

    // vimg = corrT15(img) at center
    float vimg[8];
    #pragma unroll
    for (int k = 0; k < 8; ++k) vimg[k] = 0.f;
    #pragma unroll 1
    for (int i = 0; i < 15; ++i) {
        const float* rowp = ub + (oy + 7 + i) * SPW + ox + 4;
        float seg[28];
        #pragma unroll
        for (int q = 0; q < 7; ++q) *(float4*)(seg + 4 * q) = *(const float4*)(rowp + 4 * q);
        float kv[16];
        #pragma unroll
        for (int q = 0; q < 4; ++q) *(float4*)(kv + 4 * q) = *(const float4*)(ktf + i * 16 + 4 * q);
        #pragma unroll
        for (int j = 0; j < 15; ++j)
            #pragma unroll
            for (int k = 0; k < 8; ++k) vimg[k] = fmaf(seg[j + k + 3], kv[j], vimg[k]);
    }

    // phase 1a: t0 = corr15(img) -> regs
    const int s0 = tid, s1i = tid + 256;
    const int row0 = s0 / 10, ca0 = (s0 - row0 * 10) << 3;
    const int row1 = s1i / 10, ca1 = (s1i - row1 * 10) << 3;
    const bool av1 = (s1i < 460);
    float a0[8], a1[8];
    #pragma unroll
    for (int k = 0; k < 8; ++k) { a0[k] = 0.f; a1[k] = 0.f; }
    #pragma unroll 1
    for (int i = 0; i < 15; ++i) {
        float kv[16];
        #pragma unroll
        for (int q = 0; q < 4; ++q) *(float4*)(kv + 4 * q) = *(const float4*)(kt + i * 16 + 4 * q);
        {
            const float* rp = ub + (row0 + i) * SPW + ca0;
            float seg[24];
            #pragma unroll
            for (int q = 0; q < 6; ++q) *(float4*)(seg + 4 * q) = *(const float4*)(rp + 4 * q);
            #pragma unroll
            for (int j = 0; j < 15; ++j)
                #pragma unroll
                for (int k = 0; k < 8; ++k) a0[k] = fmaf(seg[j + k], kv[j], a0[k]);
        }
        if (av1) {
            const float* rp = ub + (row1 + i) * SPW + ca1;
            float seg[24];
            #pragma unroll
            for (int q = 0; q < 6; ++q) *(float4*)(seg + 4 * q) = *(const float4*)(rp + 4 * q);
            #pragma unroll
            for (int j = 0; j < 15; ++j)
                #pragma unroll
                for (int k = 0; k < 8; ++k) a1[k] = fmaf(seg[j + k], kv[j], a1[k]);
        }
    }
    {
        const int gy = by - 7 + row0, gxb = bx - 7 + ca0;
        #pragma unroll
        for (int k = 0; k < 8; ++k)
            if (((unsigned)gy >= (unsigned)H) || ((unsigned)(gxb + k) >= (unsigned)W)) a0[k] = 0.f;
    }
    if (av1) {
        const int gy = by - 7 + row1, gxb = bx - 7 + ca1;
        #pragma unroll
        for (int k = 0; k < 8; ++k)
            if (((unsigned)gy >= (unsigned)H) || ((unsigned)(gxb + k) >= (unsigned)W)) a1[k] = 0.f;
    }
    __syncthreads();
    {
        float* o = ub + row0 * S0W + ca0;
        *(float4*)(o) = make_float4(a0[0], a0[1], a0[2], a0[3]);
        *(float4*)(o + 4) = make_float4(a0[4], a0[5], a0[6], a0[7]);
    }
    if (av1) {
        float* o = ub + row1 * S0W + ca1;
        *(float4*)(o) = make_float4(a1[0], a1[1], a1[2], a1[3]);
        *(float4*)(o + 4) = make_float4(a1[4], a1[5], a1[6], a1[7]);
    }
    __syncthreads();

    // phase 2: adjoint
    float acc[8];
    #pragma unroll
    for (int k = 0; k < 8; ++k) acc[k] = 0.f;
    #pragma unroll 1
    for (int i = 0; i < 15; ++i) {
        float kv[16];
        #pragma unroll
        for (int q = 0; q < 4; ++q) *(float4*)(kv + 4 * q) = *(const float4*)(ktf + i * 16 + 4 * q);
        const float* rp = ub + (oy + i) * S0W + ox;
        float seg[24];
        #pragma unroll
        for (int q = 0; q < 6; ++q) *(float4*)(seg + 4 * q) = *(const float4*)(rp + 4 * q);
        #pragma unroll
        for (int j = 0; j < 15; ++j)
            #pragma unroll
            for (int k = 0; k < 8; ++k) acc[k] = fmaf(seg[j + k], kv[j], acc[k]);
    }
    float accB[8], accC[8];
    #pragma unroll
    for (int k = 0; k < 8; ++k) { accB[k] = 0.f; accC[k] = 0.f; }
    #pragma unroll 1
    for (int i = 0; i < 5; ++i) {
        float kb[8], kc[8];
        #pragma unroll
        for (int q = 0; q < 2; ++q) {
            *(float4*)(kb + 4 * q) = *(const float4*)(rktf + i * 8 + 4 * q);
            *(float4*)(kc + 4 * q) = *(const float4*)(rktf + 40 + i * 8 + 4 * q);
        }
        const float* r1p = st1 + (oy + i) * S1W + ox;
        const float* r2p = st2 + (oy + i) * S1W + ox;
        float sA[12], sB[12];
        #pragma unroll
        for (int q = 0; q < 3; ++q) *(float4*)(sA + 4 * q) = *(const float4*)(r1p + 4 * q);
        #pragma unroll
        for (int q = 0; q < 3; ++q) *(float4*)(sB + 4 * q) = *(const float4*)(r2p + 4 * q);
        #pragma unroll
        for (int j = 0; j < 5; ++j)
            #pragma unroll
            for (int k = 0; k < 8; ++k) {
                accB[k] = fmaf(sA[j + k], kb[j], accB[k]);
                accC[k] = fmaf(sB[j + k], kc[j], accC[k]);
            }
    }

    float v[8];
    #pragma unroll
    for (int k = 0; k < 8; ++k) v[k] = vimg[k] - (acc[k] + w02 * accB[k] + w12 * accC[k]);

    const int g = c * HW + (by + oy) * W + bx + ox;
    *(float4*)(outR + g)     = make_float4(v[0], v[1], v[2], v[3]);
    *(float4*)(outR + g + 4) = make_float4(v[4], v[5], v[6], v[7]);
    *(float4*)(outP + g)     = make_float4(v[0], v[1], v[2], v[3]);
    *(float4*)(outP + g + 4) = make_float4(v[4], v[5], v[6], v[7]);
    *(float4*)(outX + g)     = make_float4(pctr[0], pctr[1], pctr[2], pctr[3]);
    *(float4*)(outX + g + 4) = make_float4(pctr[4], pctr[5], pctr[6], pctr[7]);
    float local = 0.f;
    #pragma unroll
    for (int k = 0; k < 8; ++k) local += v[k] * v[k];
    const float tot = block_reduce_256(local, redbuf);
    if (tid == 0) {
        const int bid = blockIdx.y * gridDim.x + blockIdx.x;
        atomicAdd(red + (bid & (NSLOT - 1)) * SSTR + c, tot);
    }
}

// ---------------- K1: merged interior+edge A-apply with folded p/x update ----------------
// i==0 (FIRST): pe = p0 (pold), no state writes. i>=1: beta_{i-1}=rtr_i/rtr_{i-1},
// alpha_{i-1}=rtr_{i-1}/ptap_{i-1}; pe = r_i + beta*p_{i-1}; own-tile: pnew=pe, x+=alpha*p_{i-1}.
// Computes Ap_i = A(pe) and reduces ptap_i = pe.Ap_i (from actual values).
template <bool FIRST>
__global__ __launch_bounds__(256) void stepA_k(
    const float* __restrict__ pold, const float* __restrict__ rvec,
    float* __restrict__ x, const float* __restrict__ taps,
    float* __restrict__ Apnew, float* __restrict__ pnew,
    const float* __restrict__ rtrI, const float* __restrict__ rtrIm1,
    const float* __restrict__ ptapIm1, float* __restrict__ ptapI)
{
    __shared__ __align__(16) float lds[LDSE];
    __shared__ float redbuf[4];
    const int c = blockIdx.z;
    const int tid = threadIdx.x;
    const int bid = blockIdx.x;

    float alpha = 0.f, beta = 0.f;
    if (!FIRST) {
        const float ri   = sum_slots(rtrI, c);
        const float rim1 = sum_slots(rtrIm1, c);
        const float ptm1 = sum_slots(ptapIm1, c);
        beta  = ri / (rim1 + EPS);
        alpha = rim1 / (ptm1 + EPS);
    }

    float S1 = 0.f;

    if (bid < 68) {
        // ================= EDGE role (two-pass, exact boundaries) =================
        float* ub  = lds;
        float* st1 = lds + UBUF;
        float* st2 = st1 + S1H * S1W;
        const float* kt   = taps;
        const float* ktf  = taps + 240;
        const float* rkt  = taps + 480;
        const float* rktf = taps + 560;
        const float w02 = taps[1684], w12 = taps[1685];

        int tbx, tby;
        { const int e = bid;
          if (e < 12)      { tbx = e;      tby = 0; }
          else if (e < 24) { tbx = e - 12; tby = 23; }
          else if (e < 46) { tbx = 0;      tby = 1 + (e - 24); }
          else             { tbx = 11;     tby = 1 + (e - 46); } }
        const int bx = tbx * 64, by = tby * 32;

        for (int s = tid; s < SPH * 96; s += 256) {
            const int ly = s / 96, lx = s - ly * 96;
            const int gy = by - 14 + ly, gx = bx - 14 + lx;
            float pe = 0.f;
            if ((unsigned)gy < (unsigned)H && (unsigned)gx < (unsigned)W) {
                const int g = c * HW + gy * W + gx;
                const float pv = pold[g];
                if (FIRST) pe = pv;
                else {
                    pe = fmaf(beta, pv, rvec[g]);
                    if (ly >= 14 && ly < 46 && lx >= 14 && lx < 78) {
                        pnew[g] = pe;
                        x[g] = fmaf(alpha, pv, x[g]);
                    }
                }
            }
            ub[ly * SPW + lx] = pe;
        }
        __syncthreads();

        const int oy = tid >> 3;
        const int ox = (tid & 7) << 3;

        // phase 1b
        {
            const int s0 = tid, s1i = tid + 256;
            const int row0 = s0 / 9, c0 = (s0 - row0 * 9) << 3;
            const int row1 = s1i / 9, c1 = (s1i - row1 * 9) << 3;
            const bool v1 = (s1i < 324);
            float b0[8], c0a[8], b1[8], c1a[8];
            #pragma unroll
            for (int k = 0; k < 8; ++k) { b0[k] = 0.f; c0a[k] = 0.f; b1[k] = 0.f; c1a[k] = 0.f; }
            #pragma unroll 1
            for (int i = 0; i < 5; ++i) {
                float kb[8], kc[8];
                #pragma unroll
                for (int q = 0; q < 2; ++q) {
                    *(float4*)(kb + 4 * q) = *(const float4*)(rkt + i * 8 + 4 * q);
                    *(float4*)(kc + 4 * q) = *(const float4*)(rkt + 40 + i * 8 + 4 * q);
                }
                {
                    const float* rp = ub + (row0 + 10 + i) * SPW + c0 + 8;
                    float seg[16];
                    #pragma unroll
                    for (int q = 0; q < 4; ++q) *(float4*)(seg + 4 * q) = *(const float4*)(rp + 4 * q);
                    #pragma unroll
                    for (int j = 0; j < 5; ++j)
                        #pragma unroll
                        for (int k = 0; k < 8; ++k) {
                            b0[k]  = fmaf(seg[j + k + 2], kb[j], b0[k]);
                            c0a[k] = fmaf(seg[j + k + 2], kc[j], c0a[k]);
                        }
                }
                if (v1) {
                    const float* rp = ub + (row1 + 10 + i) * SPW + c1 + 8;
                    float seg[16];
                    #pragma unroll
                    for (int q = 0; q < 4; ++q) *(float4*)(seg + 4 * q) = *(const float4*)(rp + 4 * q);
                    #pragma unroll
                    for (int j = 0; j < 5; ++j)
                        #pragma unroll
                        for (int k = 0; k < 8; ++k) {
                            b1[k]  = fmaf(seg[j + k + 2], kb[j], b1[k]);
                            c1a[k] = fmaf(seg[j + k + 2], kc[j], c1a[k]);
                        }
                }
            }
            {
                const int gy = by - 2 + row0, gxb = bx - 2 + c0;
                #pragma unroll
                for (int k = 0; k < 8; ++k)
                    if (((unsigned)gy >= (unsigned)H) || ((unsigned)(gxb + k) >= (unsigned)W)) { b0[k] = 0.f; c0a[k] = 0.f; }
                float* o1 = st1 + row0 * S1W + c0;
                float* o2 = st2 + row0 * S1W + c0;
                *(float4*)(o1) = make_float4(b0[0], b0[1], b0[2], b0[3]);
                *(float4*)(o1 + 4) = make_float4(b0[4], b0[5], b0[6], b0[7]);
                *(float4*)(o2) = make_float4(c0a[0], c0a[1], c0a[2], c0a[3]);
                *(float4*)(o2 + 4) = make_float4(c0a[4], c0a[5], c0a[6], c0a[7]);
            }
            if (v1) {
                const int gy = by - 2 + row1, gxb = bx - 2 + c1;
                #pragma unroll
                for (int k = 0; k < 8; ++k)
                    if (((unsigned)gy >= (unsigned)H) || ((unsigned)(gxb + k) >= (unsigned)W)) { b1[k] = 0.f; c1a[k] = 0.f; }
                float* o1 = st1 + row1 * S1W + c1;
                float* o2 = st2 + row1 * S1W + c1;
                *(float4*)(o1) = make_float4(b1[0], b1[1], b1[2], b1[3]);
                *(float4*)(o1 + 4) = make_float4(b1[4], b1[5], b1[6], b1[7]);
                *(float4*)(o2) = make_float4(c1a[0], c1a[1], c1a[2], c1a[3]);
                *(float4*)(o2 + 4) = make_float4(c1a[4], c1a[5], c1a[6], c1a[7]);
            }
        }

        float pctr[8];
        {
            const float* ctr = ub + (oy + 14) * SPW + ox + 14;
            #pragma unroll
            for (int k = 0; k < 8; ++k) pctr[k] = ctr[k];
        }

        // phase 1a
        const int s0 = tid, s1i = tid + 256;
        const int row0 = s0 / 10, ca0 = (s0 - row0 * 10) << 3;
        const int row1 = s1i / 10, ca1 = (s1i - row1 * 10) << 3;
        const bool av1 = (s1i < 460);
        float a0[8], a1[8];
        #pragma unroll
        for (int k = 0; k < 8; ++k) { a0[k] = 0.f; a1[k] = 0.f; }
        #pragma unroll 1
        for (int i = 0; i < 15; ++i) {
            float kv[16];
            #pragma unroll
            for (int q = 0; q < 4; ++q) *(float4*)(kv + 4 * q) = *(const float4*)(kt + i * 16 + 4 * q);
            {
                const float* rp = ub + (row0 + i) * SPW + ca0;
                float seg[24];
                #pragma unroll
                for (int q = 0; q < 6; ++q) *(float4*)(seg + 4 * q) = *(const float4*)(rp + 4 * q);
                #pragma unroll
                for (int j = 0; j < 15; ++j)
                    #pragma unroll
                    for (int k = 0; k < 8; ++k) a0[k] = fmaf(seg[j + k], kv[j], a0[k]);
            }
            if (av1) {
                const float* rp = ub + (row1 + i) * SPW + ca1;
                float seg[24];
                #pragma unroll
                for (int q = 0; q < 6; ++q) *(float4*)(seg + 4 * q) = *(const float4*)(rp + 4 * q);
                #pragma unroll
                for (int j = 0; j < 15; ++j)
                    #pragma unroll
                    for (int k = 0; k < 8; ++k) a1[k] = fmaf(seg[j + k], kv[j], a1[k]);
            }
        }
        {
            const int gy = by - 7 + row0, gxb = bx - 7 + ca0;
            #pragma unroll
            for (int k = 0; k < 8; ++k)
                if (((unsigned)gy >= (unsigned)H) || ((unsigned)(gxb + k) >= (unsigned)W)) a0[k] = 0.f;
        }
        if (av1) {
            const int gy = by - 7 + row1, gxb = bx - 7 + ca1;
            #pragma unroll
            for (int k = 0; k < 8; ++k)
                if (((unsigned)gy >= (unsigned)H) || ((unsigned)(gxb + k) >= (unsigned)W)) a1[k] = 0.f;
        }
        __syncthreads();
        {
            float* o = ub + row0 * S0W + ca0;
            *(float4*)(o) = make_float4(a0[0], a0[1], a0[2], a0[3]);
            *(float4*)(o + 4) = make_float4(a0[4], a0[5], a0[6], a0[7]);
        }
        if (av1) {
            float* o = ub + row1 * S0W + ca1;
            *(float4*)(o) = make_float4(a1[0], a1[1], a1[2], a1[3]);
            *(float4*)(o + 4) = make_float4(a1[4], a1[5], a1[6], a1[7]);
        }
        __syncthreads();

        // phase 2
        float acc[8];
        #pragma unroll
        for (int k = 0; k < 8; ++k) acc[k] = 0.f;
        #pragma unroll 1
        for (int i = 0; i < 15; ++i) {
            float kv[16];
            #pragma unroll
            for (int q = 0; q < 4; ++q) *(float4*)(kv + 4 * q) = *(const float4*)(ktf + i * 16 + 4 * q);
            const float* rp = ub + (oy + i) * S0W + ox;
            float seg[24];
            #pragma unroll
            for (int q = 0; q < 6; ++q) *(float4*)(seg + 4 * q) = *(const float4*)(rp + 4 * q);
            #pragma unroll
            for (int j = 0; j < 15; ++j)
                #pragma unroll
                for (int k = 0; k < 8; ++k) acc[k] = fmaf(seg[j + k], kv[j], acc[k]);
        }
        float accB[8], accC[8];
        #pragma unroll
        for (int k = 0; k < 8; ++k) { accB[k] = 0.f; accC[k] = 0.f; }
        #pragma unroll 1
        for (int i = 0; i < 5; ++i) {
            float kb[8], kc[8];
            #pragma unroll
            for (int q = 0; q < 2; ++q) {
                *(float4*)(kb + 4 * q) = *(const float4*)(rktf + i * 8 + 4 * q);
                *(float4*)(kc + 4 * q) = *(const float4*)(rktf + 40 + i * 8 + 4 * q);
            }
            const float* r1p = st1 + (oy + i) * S1W + ox;
            const float* r2p = st2 + (oy + i) * S1W + ox;
            float sA[12], sB[12];
            #pragma unroll
            for (int q = 0; q < 3; ++q) *(float4*)(sA + 4 * q) = *(const float4*)(r1p + 4 * q);
            #pragma unroll
            for (int q = 0; q < 3; ++q) *(float4*)(sB + 4 * q) = *(const float4*)(r2p + 4 * q);
            #pragma unroll
            for (int j = 0; j < 5; ++j)
                #pragma unroll
                for (int k = 0; k < 8; ++k) {
                    accB[k] = fmaf(sA[j + k], kb[j], accB[k]);
                    accC[k] = fmaf(sB[j + k], kc[j], accC[k]);
                }
        }

        float v[8];
        #pragma unroll
        for (int k = 0; k < 8; ++k) v[k] = acc[k] + w02 * accB[k] + w12 * accC[k];

        const int g = c * HW + (by + oy) * W + bx + ox;
        *(float4*)(Apnew + g)     = make_float4(v[0], v[1], v[2], v[3]);
        *(float4*)(Apnew + g + 4) = make_float4(v[4], v[5], v[6], v[7]);
        #pragma unroll
        for (int k = 0; k < 8; ++k) S1 += pctr[k] * v[k];
    } else {
        // ================= INTERIOR role (composed 29x29) =================
        const float* tk = taps + 640;
        const int b = bid - 68;
        const int bx = 64 + (b % 10) * 64, by = 32 + (b / 10) * 32;
        const int gy0 = by - 14, gx0 = bx - 14;

        for (int s = tid; s < IPH * IPW; s += 256) {
            const int ly = s / IPW, lx = s - ly * IPW;
            const int g = c * HW + (gy0 + ly) * W + (gx0 + lx);
            const float pv = pold[g];
            float pe;
            if (FIRST) pe = pv;
            else {
                pe = fmaf(beta, pv, rvec[g]);
                if (ly >= 14 && ly < 46 && lx >= 14 && lx < 78) {
                    pnew[g] = pe;
                    x[g] = fmaf(alpha, pv, x[g]);
                }
            }
            lds[s] = pe;
        }
        __syncthreads();

        const int ox = (tid & 15) << 2;
        const int o0 = (tid >> 4) << 1;

        float a0[4], a1[4];
        #pragma unroll
        for (int k = 0; k < 4; ++k) { a0[k] = 0.f; a1[k] = 0.f; }
        {
            const float* rp = lds + o0 * IPW + ox;
            float seg[32];
            #pragma unroll
            for (int q = 0; q < 8; ++q) *(float4*)(seg + 4 * q) = *(const float4*)(rp + 4 * q);
            #pragma unroll
            for (int j = 0; j < 29; ++j) {
                const float kv = tk[j];
                #pragma unroll
                for (int k = 0; k < 4; ++k) a0[k] = fmaf(seg[j + k], kv, a0[k]);
            }
        }
        #pragma unroll 1
        for (int d = 1; d <= 28; ++d) {
            const float* rp = lds + (o0 + d) * IPW + ox;
            float seg[32];
            #pragma unroll
            for (int q = 0; q < 8; ++q) *(float4*)(seg + 4 * q) = *(const float4*)(rp + 4 * q);
            const float* kr0 = tk + d * 36;
            const float* kr1 = kr0 - 36;
            #pragma unroll
            for (int j = 0; j < 29; ++j) {
                const float kv0 = kr0[j], kv1 = kr1[j];
                #pragma unroll
                for (int k = 0; k < 4; ++k) {
                    a0[k] = fmaf(seg[j + k], kv0, a0[k]);
                    a1[k] = fmaf(seg[j + k], kv1, a1[k]);
                }
            }
        }
        {
            const float* rp = lds + (o0 + 29) * IPW + ox;
            float seg[32];
            #pragma unroll
            for (int q = 0; q < 8; ++q) *(float4*)(seg + 4 * q) = *(const float4*)(rp + 4 * q);
            const float* kr1 = tk + 28 * 36;
            #pragma unroll
            for (int j = 0; j < 29; ++j) {
                const float kv = kr1[j];
                #pragma unroll
                for (int k = 0; k < 4; ++k) a1[k] = fmaf(seg[j + k], kv, a1[k]);
            }
        }

        const int gbase = c * HW + (by + o0) * W + bx + ox;
        const float* c0p = lds + (o0 + 14) * IPW + ox + 14;
        const float* c1p = c0p + IPW;
        *(float4*)(Apnew + gbase)     = make_float4(a0[0], a0[1], a0[2], a0[3]);
        *(float4*)(Apnew + gbase + W) = make_float4(a1[0], a1[1], a1[2], a1[3]);
        #pragma unroll
        for (int k = 0; k < 4; ++k) S1 += c0p[k] * a0[k] + c1p[k] * a1[k];
    }

    const float tot = block_reduce_256(S1, redbuf);
    if (tid == 0) atomicAdd(ptapI + (bid & (NSLOT - 1)) * SSTR + c, tot);
}

// ---------------- K2: r -= alpha*Ap (in-place); reduce ||r_new||^2 from values ----------------
__global__ __launch_bounds__(256) void cgr_k(
    float* __restrict__ r, const float* __restrict__ Ap,
    const float* __restrict__ rtrI, const float* __restrict__ ptapI,
    float* __restrict__ rtrNext)
{
    __shared__ float redbuf[4];
    const int c = blockIdx.z;
    const float alpha = sum_slots(rtrI, c) / (sum_slots(ptapI, c) + EPS);
    const int idx = c * HW + (blockIdx.x * 256 + threadIdx.x) * 8;
    float local = 0.f;
    #pragma unroll
    for (int h = 0; h < 2; ++h) {
        const int o = idx + 4 * h;
        float4 rv = *(float4*)(r + o);
        const float4 av = *(const float4*)(Ap + o);
        rv.x = fmaf(-alpha, av.x, rv.x);
        rv.y = fmaf(-alpha, av.y, rv.y);
        rv.z = fmaf(-alpha, av.z, rv.z);
        rv.w = fmaf(-alpha, av.w, rv.w);
        *(float4*)(r + o) = rv;
        local += rv.x * rv.x + rv.y * rv.y + rv.z * rv.z + rv.w * rv.w;
    }
    const float tot = block_reduce_256(local, redbuf);
    if (threadIdx.x == 0)
        atomicAdd(rtrNext + ((int)blockIdx.x & (NSLOT - 1)) * SSTR + c, tot);
}

// ---------------- epilogue: x100 = x99 + a99*p99; p100 = r100 + b99*p99 ----------------
__global__ __launch_bounds__(256) void ep_k(
    float* __restrict__ x, const float* __restrict__ r100, const float* __restrict__ p99,
    float* __restrict__ pout,
    const float* __restrict__ rtr99s, const float* __restrict__ rtr100s,
    const float* __restrict__ ptap99s)
{
    const int c = blockIdx.z;
    const float rtr99 = sum_slots(rtr99s, c);
    const float alpha = rtr99 / (sum_slots(ptap99s, c) + EPS);
    const float beta  = sum_slots(rtr100s, c) / (rtr99 + EPS);
    const int idx = c * HW + (blockIdx.x * 256 + threadIdx.x) * 8;
    #pragma unroll
    for (int h = 0; h < 2; ++h) {
        const int o = idx + 4 * h;
        const float4 pv = *(const float4*)(p99 + o);
        const float4 rv = *(const float4*)(r100 + o);
        float4 xv = *(float4*)(x + o);
        xv.x = fmaf(alpha, pv.x, xv.x); xv.y = fmaf(alpha, pv.y, xv.y);
        xv.z = fmaf(alpha, pv.z, xv.z); xv.w = fmaf(alpha, pv.w, xv.w);
        *(float4*)(x + o) = xv;
        *(float4*)(pout + o) = make_float4(
            fmaf(beta, pv.x, rv.x), fmaf(beta, pv.y, rv.y),
            fmaf(beta, pv.z, rv.z), fmaf(beta, pv.w, rv.w));
    }
}

extern "C" void kernel_launch(void* const* d_in, const int* in_sizes, int n_in,
                              void* d_out, int out_size, void* d_ws, size_t ws_size,
                              hipStream_t stream)
{
    const float* img = (const float*)d_in[0];
    const float* k15 = (const float*)d_in[1];
    const float* rks = (const float*)d_in[2];
    const float* rw  = (const float*)d_in[3];

    float* out = (float*)d_out;
    float* xs = out;            // x (updated in place across iterations)
    float* rs = out + CHW;      // r (updated in place)
    float* ps = out + 2 * CHW;  // final p_100

    float* ws = (float*)d_ws;
    float* pA   = ws;               // p parity 0 (p0, p2, ...)
    float* pB   = ws + CHW;         // p parity 1 (p1, p3, ...)
    float* Ap   = ws + 2 * CHW;
    float* scal = ws + 3 * CHW;
    float* rtrS  = scal;                      // 101 * SCALSZ
    float* ptapS = scal + 101 * SCALSZ;       // 100 * SCALSZ
    float* taps  = scal + 201 * SCALSZ;       // 1688

    float* pbuf[2] = { pA, pB };

    hipMemsetAsync(scal, 0, (size_t)201 * SCALSZ * sizeof(float), stream);
    tap_prep_k<<<1, 256, 0, stream>>>(k15, rks, rw, taps);

    const dim3 bc(256);
    prologue_k<<<dim3(12, 24, 3), bc, 0, stream>>>(img, taps, rs, pA, xs, rtrS);

    for (int i = 0; i < 100; ++i) {
        if (i == 0) {
            stepA_k<true><<<dim3(288, 1, 3), bc, 0, stream>>>(
                pA, rs, xs, taps, Ap, nullptr,
                rtrS, rtrS, ptapS, ptapS);
        } else {
            stepA_k<false><<<dim3(288, 1, 3), bc, 0, stream>>>(
                pbuf[(i - 1) & 1], rs, xs, taps, Ap, pbuf[i & 1],
                rtrS + (size_t)i * SCALSZ, rtrS + (size_t)(i - 1) * SCALSZ,
                ptapS + (size_t)(i - 1) * SCALSZ, ptapS + (size_t)i * SCALSZ);
        }
        cgr_k<<<dim3(288, 1, 3), bc, 0, stream>>>(
            rs, Ap, rtrS + (size_t)i * SCALSZ, ptapS + (size_t)i * SCALSZ,
            rtrS + (size_t)(i + 1) * SCALSZ);
    }
    // p_99 is in pbuf[99 & 1] = pB; r_100 in rs
    ep_k<<<dim3(288, 1, 3), bc, 0, stream>>>(
        xs, rs, pB, ps,
        rtrS + (size_t)99 * SCALSZ, rtrS + (size_t)100 * SCALSZ,
        ptapS + (size_t)99 * SCALSZ);
}

// Round 9
// 8736.208 us; speedup vs baseline: 1.2245x; 1.0009x over previous
//
#include <hip/hip_runtime.h>

#define EPS 1e-12f

constexpr int H = 768, W = 768, C = 3;
constexpr int HW = H * W;
constexpr int CHW = C * HW;

constexpr int NSLOT = 16;
constexpr int SSTR = 16;
constexpr int SCALSZ = NSLOT * SSTR;

// prologue (full 64x32 two-pass) geometry — unchanged, runs once
constexpr int SPW = 100, SPH = 60;
constexpr int S0W = 84;
constexpr int S1W = 76, S1H = 36;
constexpr int UBUF = SPH * SPW;

// stepA edge strips: 64x16 output, two-pass
constexpr int ESPH = 44;                   // pe rows (16 + 28)
constexpr int ET0H = 30;                   // t0 rows (16 + 14)
constexpr int ES1H = 20;                   // t1/t2 rows (16 + 4)
constexpr int ELDS = ESPH * SPW + 2 * ES1H * S1W;  // 4400 + 3040 = 7440 floats (29.8 KB)
// stepA interior: composed 29x29 on 64x32
constexpr int IPW = 92, IPH = 60;          // 5520 floats (22.1 KB)
constexpr int NEDGE = 136;                 // 68 tiles x 2 strips

__device__ __forceinline__ float block_reduce_256(float v, float* redbuf) {
    #pragma unroll
    for (int off = 32; off > 0; off >>= 1) v += __shfl_down(v, off, 64);
    const int tid = threadIdx.x;
    if ((tid & 63) == 0) redbuf[tid >> 6] = v;
    __syncthreads();
    return redbuf[0] + redbuf[1] + redbuf[2] + redbuf[3];
}

__device__ __forceinline__ float sum_slots(const float* base, int c) {
    float s = 0.f;
    #pragma unroll
    for (int k = 0; k < NSLOT; ++k) s += base[k * SSTR + c];
    return s;
}

// taps: [0..239] k15 fwd (15x16), [240..479] k15 flip, [480..559] rk fwd (2x5x8),
// [560..639] rk flip, [640..1683] TK 29x36 composed, [1684] w0^2, [1685] w1^2
__global__ void tap_prep_k(const float* __restrict__ k15, const float* __restrict__ rks,
                           const float* __restrict__ rw, float* __restrict__ taps) {
    const int tid = threadIdx.x;
    if (tid < 240) {
        const int i = tid >> 4, j = tid & 15;
        taps[tid]       = (j < 15) ? k15[i * 15 + j] : 0.f;
        taps[240 + tid] = (j < 15) ? k15[(14 - i) * 15 + (14 - j)] : 0.f;
    }
    if (tid < 80) {
        const int kk = tid / 40, rem = tid % 40, i = rem >> 3, j = rem & 7;
        taps[480 + tid] = (j < 5) ? rks[kk * 25 + i * 5 + j] : 0.f;
        taps[560 + tid] = (j < 5) ? rks[kk * 25 + (4 - i) * 5 + (4 - j)] : 0.f;
    }
    const float w20 = rw[0] * rw[0], w21 = rw[1] * rw[1];
    if (tid == 0) { taps[1684] = w20; taps[1685] = w21; }
    for (int t = tid; t < 29 * 36; t += 256) {
        const int uy = t / 36, ux = t - uy * 36;
        float s = 0.f;
        if (ux < 29) {
            const int dy = uy - 14, dx = ux - 14;
            for (int sy = 0; sy < 15; ++sy) {
                const int ty = sy + dy;
                if ((unsigned)ty >= 15u) continue;
                for (int sx = 0; sx < 15; ++sx) {
                    const int tx = sx + dx;
                    if ((unsigned)tx < 15u) s += k15[sy * 15 + sx] * k15[ty * 15 + tx];
                }
            }
            if (dy >= -4 && dy <= 4 && dx >= -4 && dx <= 4) {
                float q0 = 0.f, q1 = 0.f;
                for (int sy = 0; sy < 5; ++sy) {
                    const int ty = sy + dy;
                    if ((unsigned)ty >= 5u) continue;
                    for (int sx = 0; sx < 5; ++sx) {
                        const int tx = sx + dx;
                        if ((unsigned)tx >= 5u) continue;
                        q0 += rks[sy * 5 + sx] * rks[ty * 5 + tx];
                        q1 += rks[25 + sy * 5 + sx] * rks[25 + ty * 5 + tx];
                    }
                }
                s += w20 * q0 + w21 * q1;
            }
        }
        taps[640 + t] = s;
    }
}

// ---------------- prologue: r0 = K^T b - A(img); p0 = r0; x0 = img; rtr0 ----------------
__global__ __launch_bounds__(256) void prologue_k(
    const float* __restrict__ img, const float* __restrict__ taps,
    float* __restrict__ outR, float* __restrict__ outP, float* __restrict__ outX,
    float* __restrict__ red)
{
    __shared__ __align__(16) float ub[UBUF];
    __shared__ __align__(16) float st1[S1H * S1W];
    __shared__ __align__(16) float st2[S1H * S1W];
    __shared__ float redbuf[4];

    const float* kt   = taps;
    const float* ktf  = taps + 240;
    const float* rkt  = taps + 480;
    const float* rktf = taps + 560;
    const float w02 = taps[1684], w12 = taps[1685];

    const int c = blockIdx.z;
    const int bx = blockIdx.x * 64, by = blockIdx.y * 32;
    const int tid = threadIdx.x;
    const float* inC = img + c * HW;

    for (int t = tid; t < SPH * 96; t += 256) {
        const int ly = t / 96, lx = t - ly * 96;
        const int gy = by - 14 + ly, gx = bx - 14 + lx;
        float v = 0.f;
        if ((unsigned)gy < (unsigned)H && (unsigned)gx < (unsigned)W) v = inC[gy * W + gx];
        ub[ly * SPW + lx] = v;
    }
    __syncthreads();

    const int oy = tid >> 3;
    const int ox = (tid & 7) << 3;

    // phase 1b
    {
        const int s0 = tid, s1i = tid + 256;
        const int row0 = s0 / 9, c0 = (s0 - row0 * 9) << 3;
        const int row1 = s1i / 9, c1 = (s1i - row1 * 9) << 3;
        const bool v1 = (s1i < 324);
        float b0[8], c0a[8], b1[8], c1a[8];
        #pragma unroll
        for (int k = 0; k < 8; ++k) { b0[k] = 0.f; c0a[k] = 0.f; b1[k] = 0.f; c1a[k] = 0.f; }
        #pragma unroll 1
        for (int i = 0; i < 5; ++i) {
            float kb[8], kc[8];
            #pragma unroll
            for (int q = 0; q < 2; ++q) {
                *(float4*)(kb + 4 * q) = *(const float4*)(rkt + i * 8 + 4 * q);
                *(float4*)(kc + 4 * q) = *(const float4*)(rkt + 40 + i * 8 + 4 * q);
            }
            {
                const float* rp = ub + (row0 + 10 + i) * SPW + c0 + 8;
                float seg[16];
                #pragma unroll
                for (int q = 0; q < 4; ++q) *(float4*)(seg + 4 * q) = *(const float4*)(rp + 4 * q);
                #pragma unroll
                for (int j = 0; j < 5; ++j)
                    #pragma unroll
                    for (int k = 0; k < 8; ++k) {
                        b0[k]  = fmaf(seg[j + k + 2], kb[j], b0[k]);
                        c0a[k] = fmaf(seg[j + k + 2], kc[j], c0a[k]);
                    }
            }
            if (v1) {
                const float* rp = ub + (row1 + 10 + i) * SPW + c1 + 8;
                float seg[16];
                #pragma unroll
                for (int q = 0; q < 4; ++q) *(float4*)(seg + 4 * q) = *(const float4*)(rp + 4 * q);
                #pragma unroll
                for (int j = 0; j < 5; ++j)
                    #pragma unroll
                    for (int k = 0; k < 8; ++k) {
                        b1[k]  = fmaf(seg[j + k + 2], kb[j], b1[k]);
                        c1a[k] = fmaf(seg[j + k + 2], kc[j], c1a[k]);
                    }
            }
        }
        {
            const int gy = by - 2 + row0, gxb = bx - 2 + c0;
            #pragma unroll
            for (int k = 0; k < 8; ++k)
                if (((unsigned)gy >= (unsigned)H) || ((unsigned)(gxb + k) >= (unsigned)W)) { b0[k] = 0.f; c0a[k] = 0.f; }
            float* o1 = st1 + row0 * S1W + c0;
            float* o2 = st2 + row0 * S1W + c0;
            *(float4*)(o1) = make_float4(b0[0], b0[1], b0[2], b0[3]);
            *(float4*)(o1 + 4) = make_float4(b0[4], b0[5], b0[6], b0[7]);
            *(float4*)(o2) = make_float4(c0a[0], c0a[1], c0a[2], c0a[3]);
            *(float4*)(o2 + 4) = make_float4(c0a[4], c0a[5], c0a[6], c0a[7]);
        }
        if (v1) {
            const int gy = by - 2 + row1, gxb = bx - 2 + c1;
            #pragma unroll
            for (int k = 0; k < 8; ++k)
                if (((unsigned)gy >= (unsigned)H) || ((unsigned)(gxb + k) >= (unsigned)W)) { b1[k] = 0.f; c1a[k] = 0.f; }
            float* o1 = st1 + row1 * S1W + c1;
            float* o2 = st2 + row1 * S1W + c1;
            *(float4*)(o1) = make_float4(b1[0], b1[1], b1[2], b1[3]);
            *(float4*)(o1 + 4) = make_float4(b1[4], b1[5], b1[6], b1[7]);
            *(float4*)(o2) = make_float4(c1a[0], c1a[1], c1a[2], c1a[3]);
            *(float4*)(o2 + 4) = make_float4(c1a[4], c1a[5], c1a[6], c1a[7]);
        }
    }

    float pctr[8];
    {
        const float* ctr = ub + (oy + 14) * SPW + ox + 14;
        #pragma unroll
        for (int k = 0; k < 8; ++k) pctr[k] = ctr[k];
    }

    // vimg = corrT15(img) at center
    float vimg[8];
    #pragma unroll
    for (int k = 0; k < 8; ++k) vimg[k] = 0.f;
    #pragma unroll 1
    for (int i = 0; i < 15; ++i) {
        const float* rowp = ub + (oy + 7 + i) * SPW + ox + 4;
        float seg[28];
        #pragma unroll
        for (int q = 0; q < 7; ++q) *(float4*)(seg + 4 * q) = *(const float4*)(rowp + 4 * q);
        float kv[16];
        #pragma unroll
        for (int q = 0; q < 4; ++q) *(float4*)(kv + 4 * q) = *(const float4*)(ktf + i * 16 + 4 * q);
        #pragma unroll
        for (int j = 0; j < 15; ++j)
            #pragma unroll
            for (int k = 0; k < 8; ++k) vimg[k] = fmaf(seg[j + k + 3], kv[j], vimg[k]);
    }

    // phase 1a
    const int s0 = tid, s1i = tid + 256;
    const int row0 = s0 / 10, ca0 = (s0 - row0 * 10) << 3;
    const int row1 = s1i / 10, ca1 = (s1i - row1 * 10) << 3;
    const bool av1 = (s1i < 460);
    float a0[8], a1[8];
    #pragma unroll
    for (int k = 0; k < 8; ++k) { a0[k] = 0.f; a1[k] = 0.f; }
    #pragma unroll 1
    for (int i = 0; i < 15; ++i) {
        float kv[16];
        #pragma unroll
        for (int q = 0; q < 4; ++q) *(float4*)(kv + 4 * q) = *(const float4*)(kt + i * 16 + 4 * q);
        {
            const float* rp = ub + (row0 + i) * SPW + ca0;
            float seg[24];
            #pragma unroll
            for (int q = 0; q < 6; ++q) *(float4*)(seg + 4 * q) = *(const float4*)(rp + 4 * q);
            #pragma unroll
            for (int j = 0; j < 15; ++j)
                #pragma unroll
                for (int k = 0; k < 8; ++k) a0[k] = fmaf(seg[j + k], kv[j], a0[k]);
        }
        if (av1) {
            const float* rp = ub + (row1 + i) * SPW + ca1;
            float seg[24];
            #pragma unroll
            for (int q = 0; q < 6; ++q) *(float4*)(seg + 4 * q) = *(const float4*)(rp + 4 * q);
            #pragma unroll
            for (int j = 0; j < 15; ++j)
                #pragma unroll
                for (int k = 0; k < 8; ++k) a1[k] = fmaf(seg[j + k], kv[j], a1[k]);
        }
    }
    {
        const int gy = by - 7 + row0, gxb = bx - 7 + ca0;
        #pragma unroll
        for (int k = 0; k < 8; ++k)
            if (((unsigned)gy >= (unsigned)H) || ((unsigned)(gxb + k) >= (unsigned)W)) a0[k] = 0.f;
    }
    if (av1) {
        const int gy = by - 7 + row1, gxb = bx - 7 + ca1;
        #pragma unroll
        for (int k = 0; k < 8; ++k)
            if (((unsigned)gy >= (unsigned)H) || ((unsigned)(gxb + k) >= (unsigned)W)) a1[k] = 0.f;
    }
    __syncthreads();
    {
        float* o = ub + row0 * S0W + ca0;
        *(float4*)(o) = make_float4(a0[0], a0[1], a0[2], a0[3]);
        *(float4*)(o + 4) = make_float4(a0[4], a0[5], a0[6], a0[7]);
    }
    if (av1) {
        float* o = ub + row1 * S0W + ca1;
        *(float4*)(o) = make_float4(a1[0], a1[1], a1[2], a1[3]);
        *(float4*)(o + 4) = make_float4(a1[4], a1[5], a1[6], a1[7]);
    }
    __syncthreads();

    // phase 2
    float acc[8];
    #pragma unroll
    for (int k = 0; k < 8; ++k) acc[k] = 0.f;
    #pragma unroll 1
    for (int i = 0; i < 15; ++i) {
        float kv[16];
        #pragma unroll
        for (int q = 0; q < 4; ++q) *(float4*)(kv + 4 * q) = *(const float4*)(ktf + i * 16 + 4 * q);
        const float* rp = ub + (oy + i) * S0W + ox;
        float seg[24];
        #pragma unroll
        for (int q = 0; q < 6; ++q) *(float4*)(seg + 4 * q) = *(const float4*)(rp + 4 * q);
        #pragma unroll
        for (int j = 0; j < 15; ++j)
            #pragma unroll
            for (int k = 0; k < 8; ++k) acc[k] = fmaf(seg[j + k], kv[j], acc[k]);
    }
    float accB[8], accC[8];
    #pragma unroll
    for (int k = 0; k < 8; ++k) { accB[k] = 0.f; accC[k] = 0.f; }
    #pragma unroll 1
    for (int i = 0; i < 5; ++i) {
        float kb[8], kc[8];
        #pragma unroll
        for (int q = 0; q < 2; ++q) {
            *(float4*)(kb + 4 * q) = *(const float4*)(rktf + i * 8 + 4 * q);
            *(float4*)(kc + 4 * q) = *(const float4*)(rktf + 40 + i * 8 + 4 * q);
        }
        const float* r1p = st1 + (oy + i) * S1W + ox;
        const float* r2p = st2 + (oy + i) * S1W + ox;
        float sA[12], sB[12];
        #pragma unroll
        for (int q = 0; q < 3; ++q) *(float4*)(sA + 4 * q) = *(const float4*)(r1p + 4 * q);
        #pragma unroll
        for (int q = 0; q < 3; ++q) *(float4*)(sB + 4 * q) = *(const float4*)(r2p + 4 * q);
        #pragma unroll
        for (int j = 0; j < 5; ++j)
            #pragma unroll
            for (int k = 0; k < 8; ++k) {
                accB[k] = fmaf(sA[j + k], kb[j], accB[k]);
                accC[k] = fmaf(sB[j + k], kc[j], accC[k]);
            }
    }

    float v[8];
    #pragma unroll
    for (int k = 0; k < 8; ++k) v[k] = vimg[k] - (acc[k] + w02 * accB[k] + w12 * accC[k]);

    const int g = c * HW + (by + oy) * W + bx + ox;
    *(float4*)(outR + g)     = make_float4(v[0], v[1], v[2], v[3]);
    *(float4*)(outR + g + 4) = make_float4(v[4], v[5], v[6], v[7]);
    *(float4*)(outP + g)     = make_float4(v[0], v[1], v[2], v[3]);
    *(float4*)(outP + g + 4) = make_float4(v[4], v[5], v[6], v[7]);
    *(float4*)(outX + g)     = make_float4(pctr[0], pctr[1], pctr[2], pctr[3]);
    *(float4*)(outX + g + 4) = make_float4(pctr[4], pctr[5], pctr[6], pctr[7]);
    float local = 0.f;
    #pragma unroll
    for (int k = 0; k < 8; ++k) local += v[k] * v[k];
    const float tot = block_reduce_256(local, redbuf);
    if (tid == 0) {
        const int bid = blockIdx.y * gridDim.x + blockIdx.x;
        atomicAdd(red + (bid & (NSLOT - 1)) * SSTR + c, tot);
    }
}

// ---------------- K1: merged interior+edge A-apply, p-update folded ----------------
// FIRST: pe = p0 (pold). Else: beta = rtr_i/rtr_{i-1}; pe = r_i + beta*p_{i-1};
// own-center: pnew = pe. Ap = A(pe); reduce ptap = pe.Ap.
template <bool FIRST>
__global__ __launch_bounds__(256) void stepA_k(
    const float* __restrict__ pold, const float* __restrict__ rvec,
    const float* __restrict__ taps,
    float* __restrict__ Apnew, float* __restrict__ pnew,
    const float* __restrict__ rtrI, const float* __restrict__ rtrIm1,
    float* __restrict__ ptapI)
{
    __shared__ __align__(16) float lds[ELDS];
    __shared__ float redbuf[4];
    const int c = blockIdx.z;
    const int tid = threadIdx.x;
    const int bid = blockIdx.x;

    float beta = 0.f;
    if (!FIRST) beta = sum_slots(rtrI, c) / (sum_slots(rtrIm1, c) + EPS);

    float S1 = 0.f;

    if (bid < NEDGE) {
        // ============ EDGE role: 64x16 strip, two-pass (exact boundaries) ============
        float* ub  = lds;                       // pe (44x100), then t0 (30x84)
        float* st1 = lds + ESPH * SPW;
        float* st2 = st1 + ES1H * S1W;
        const float* kt   = taps;
        const float* ktf  = taps + 240;
        const float* rkt  = taps + 480;
        const float* rktf = taps + 560;
        const float w02 = taps[1684], w12 = taps[1685];

        const int e = bid >> 1, half = bid & 1;
        int tbx, tby;
        { if (e < 12)      { tbx = e;      tby = 0; }
          else if (e < 24) { tbx = e - 12; tby = 23; }
          else if (e < 46) { tbx = 0;      tby = 1 + (e - 24); }
          else             { tbx = 11;     tby = 1 + (e - 46); } }
        const int bx = tbx * 64, by = tby * 32 + half * 16;

        // staging (rows 44 x cols 96) + folded p-update on own 64x16 center
        for (int s = tid; s < ESPH * 96; s += 256) {
            const int ly = s / 96, lx = s - ly * 96;
            const int gy = by - 14 + ly, gx = bx - 14 + lx;
            float pe = 0.f;
            if ((unsigned)gy < (unsigned)H && (unsigned)gx < (unsigned)W) {
                const int g = c * HW + gy * W + gx;
                const float pv = pold[g];
                if (FIRST) pe = pv;
                else {
                    pe = fmaf(beta, pv, rvec[g]);
                    if (ly >= 14 && ly < 30 && lx >= 14 && lx < 78) pnew[g] = pe;
                }
            }
            ub[ly * SPW + lx] = pe;
        }
        __syncthreads();

        const int oy2 = tid >> 4;            // 0..15
        const int ox2 = (tid & 15) << 2;     // 0..60

        // phase 1b: t1,t2 on 20 rows x 72 cols (180 items of 8 px, single round)
        {
            const int row0 = tid / 9, c0 = (tid - (tid / 9) * 9) << 3;
            const bool act = (tid < 180);
            float b0[8], c0a[8];
            #pragma unroll
            for (int k = 0; k < 8; ++k) { b0[k] = 0.f; c0a[k] = 0.f; }
            if (act) {
                #pragma unroll 1
                for (int i = 0; i < 5; ++i) {
                    float kb[8], kc[8];
                    #pragma unroll
                    for (int q = 0; q < 2; ++q) {
                        *(float4*)(kb + 4 * q) = *(const float4*)(rkt + i * 8 + 4 * q);
                        *(float4*)(kc + 4 * q) = *(const float4*)(rkt + 40 + i * 8 + 4 * q);
                    }
                    const float* rp = ub + (row0 + 10 + i) * SPW + c0 + 8;
                    float seg[16];
                    #pragma unroll
                    for (int q = 0; q < 4; ++q) *(float4*)(seg + 4 * q) = *(const float4*)(rp + 4 * q);
                    #pragma unroll
                    for (int j = 0; j < 5; ++j)
                        #pragma unroll
                        for (int k = 0; k < 8; ++k) {
                            b0[k]  = fmaf(seg[j + k + 2], kb[j], b0[k]);
                            c0a[k] = fmaf(seg[j + k + 2], kc[j], c0a[k]);
                        }
                }
                const int gy = by - 2 + row0, gxb = bx - 2 + c0;
                #pragma unroll
                for (int k = 0; k < 8; ++k)
                    if (((unsigned)gy >= (unsigned)H) || ((unsigned)(gxb + k) >= (unsigned)W)) { b0[k] = 0.f; c0a[k] = 0.f; }
                float* o1 = st1 + row0 * S1W + c0;
                float* o2 = st2 + row0 * S1W + c0;
                *(float4*)(o1) = make_float4(b0[0], b0[1], b0[2], b0[3]);
                *(float4*)(o1 + 4) = make_float4(b0[4], b0[5], b0[6], b0[7]);
                *(float4*)(o2) = make_float4(c0a[0], c0a[1], c0a[2], c0a[3]);
                *(float4*)(o2 + 4) = make_float4(c0a[4], c0a[5], c0a[6], c0a[7]);
            }
        }

        // stash pe center (4 px for phase 2)
        float pctr[4];
        {
            const float* ctr = ub + (oy2 + 14) * SPW + ox2 + 14;
            #pragma unroll
            for (int k = 0; k < 4; ++k) pctr[k] = ctr[k];
        }

        // phase 1a: t0 = corr15(pe) on 30 rows x 80 cols (300 items, 2 rounds)
        const int s0 = tid, s1i = tid + 256;
        const int row0 = s0 / 10, ca0 = (s0 - row0 * 10) << 3;
        const int row1 = s1i / 10, ca1 = (s1i - row1 * 10) << 3;
        const bool av1 = (s1i < 300);
        float a0[8], a1[8];
        #pragma unroll
        for (int k = 0; k < 8; ++k) { a0[k] = 0.f; a1[k] = 0.f; }
        #pragma unroll 1
        for (int i = 0; i < 15; ++i) {
            float kv[16];
            #pragma unroll
            for (int q = 0; q < 4; ++q) *(float4*)(kv + 4 * q) = *(const float4*)(kt + i * 16 + 4 * q);
            {
                const float* rp = ub + (row0 + i) * SPW + ca0;
                float seg[24];
                #pragma unroll
                for (int q = 0; q < 6; ++q) *(float4*)(seg + 4 * q) = *(const float4*)(rp + 4 * q);
                #pragma unroll
                for (int j = 0; j < 15; ++j)
                    #pragma unroll
                    for (int k = 0; k < 8; ++k) a0[k] = fmaf(seg[j + k], kv[j], a0[k]);
            }
            if (av1) {
                const float* rp = ub + (row1 + i) * SPW + ca1;
                float seg[24];
                #pragma unroll
                for (int q = 0; q < 6; ++q) *(float4*)(seg + 4 * q) = *(const float4*)(rp + 4 * q);
                #pragma unroll
                for (int j = 0; j < 15; ++j)
                    #pragma unroll
                    for (int k = 0; k < 8; ++k) a1[k] = fmaf(seg[j + k], kv[j], a1[k]);
            }
        }
        {
            const int gy = by - 7 + row0, gxb = bx - 7 + ca0;
            #pragma unroll
            for (int k = 0; k < 8; ++k)
                if (((unsigned)gy >= (unsigned)H) || ((unsigned)(gxb + k) >= (unsigned)W)) a0[k] = 0.f;
        }
        if (av1) {
            const int gy = by - 7 + row1, gxb = bx - 7 + ca1;
            #pragma unroll
            for (int k = 0; k < 8; ++k)
                if (((unsigned)gy >= (unsigned)H) || ((unsigned)(gxb + k) >= (unsigned)W)) a1[k] = 0.f;
        }
        __syncthreads();   // pe reads done
        {
            float* o = ub + row0 * S0W + ca0;
            *(float4*)(o) = make_float4(a0[0], a0[1], a0[2], a0[3]);
            *(float4*)(o + 4) = make_float4(a0[4], a0[5], a0[6], a0[7]);
        }
        if (av1) {
            float* o = ub + row1 * S0W + ca1;
            *(float4*)(o) = make_float4(a1[0], a1[1], a1[2], a1[3]);
            *(float4*)(o + 4) = make_float4(a1[4], a1[5], a1[6], a1[7]);
        }
        __syncthreads();

        // phase 2: adjoint -> 64x16 output, 4 px/thread
        float acc[4];
        #pragma unroll
        for (int k = 0; k < 4; ++k) acc[k] = 0.f;
        #pragma unroll 1
        for (int i = 0; i < 15; ++i) {
            float kv[16];
            #pragma unroll
            for (int q = 0; q < 4; ++q) *(float4*)(kv + 4 * q) = *(const float4*)(ktf + i * 16 + 4 * q);
            const float* rp = ub + (oy2 + i) * S0W + ox2;
            float seg[20];
            #pragma unroll
            for (int q = 0; q < 5; ++q) *(float4*)(seg + 4 * q) = *(const float4*)(rp + 4 * q);
            #pragma unroll
            for (int j = 0; j < 15; ++j)
                #pragma unroll
                for (int k = 0; k < 4; ++k) acc[k] = fmaf(seg[j + k], kv[j], acc[k]);
        }
        float accB[4], accC[4];
        #pragma unroll
        for (int k = 0; k < 4; ++k) { accB[k] = 0.f; accC[k] = 0.f; }
        #pragma unroll 1
        for (int i = 0; i < 5; ++i) {
            float kb[8], kc[8];
            #pragma unroll
            for (int q = 0; q < 2; ++q) {
                *(float4*)(kb + 4 * q) = *(const float4*)(rktf + i * 8 + 4 * q);
                *(float4*)(kc + 4 * q) = *(const float4*)(rktf + 40 + i * 8 + 4 * q);
            }
            const float* r1p = st1 + (oy2 + i) * S1W + ox2;
            const float* r2p = st2 + (oy2 + i) * S1W + ox2;
            float sA[8], sB[8];
            #pragma unroll
            for (int q = 0; q < 2; ++q) *(float4*)(sA + 4 * q) = *(const float4*)(r1p + 4 * q);
            #pragma unroll
            for (int q = 0; q < 2; ++q) *(float4*)(sB + 4 * q) = *(const float4*)(r2p + 4 * q);
            #pragma unroll
            for (int j = 0; j < 5; ++j)
                #pragma unroll
                for (int k = 0; k < 4; ++k) {
                    accB[k] = fmaf(sA[j + k], kb[j], accB[k]);
                    accC[k] = fmaf(sB[j + k], kc[j], accC[k]);
                }
        }

        float v[4];
        #pragma unroll
        for (int k = 0; k < 4; ++k) v[k] = acc[k] + w02 * accB[k] + w12 * accC[k];

        const int g = c * HW + (by + oy2) * W + bx + ox2;
        *(float4*)(Apnew + g) = make_float4(v[0], v[1], v[2], v[3]);
        #pragma unroll
        for (int k = 0; k < 4; ++k) S1 += pctr[k] * v[k];
    } else {
        // ============ INTERIOR role: composed 29x29 on 64x32 ============
        const float* tk = taps + 640;
        const int b = bid - NEDGE;
        const int bx = 64 + (b % 10) * 64, by = 32 + (b / 10) * 32;
        const int gy0 = by - 14, gx0 = bx - 14;

        for (int s = tid; s < IPH * IPW; s += 256) {
            const int ly = s / IPW, lx = s - ly * IPW;
            const int g = c * HW + (gy0 + ly) * W + (gx0 + lx);
            const float pv = pold[g];
            float pe;
            if (FIRST) pe = pv;
            else {
                pe = fmaf(beta, pv, rvec[g]);
                if (ly >= 14 && ly < 46 && lx >= 14 && lx < 78) pnew[g] = pe;
            }
            lds[s] = pe;
        }
        __syncthreads();

        const int ox = (tid & 15) << 2;
        const int o0 = (tid >> 4) << 1;

        float a0[4], a1[4];
        #pragma unroll
        for (int k = 0; k < 4; ++k) { a0[k] = 0.f; a1[k] = 0.f; }
        {
            const float* rp = lds + o0 * IPW + ox;
            float seg[32];
            #pragma unroll
            for (int q = 0; q < 8; ++q) *(float4*)(seg + 4 * q) = *(const float4*)(rp + 4 * q);
            #pragma unroll
            for (int j = 0; j < 29; ++j) {
                const float kv = tk[j];
                #pragma unroll
                for (int k = 0; k < 4; ++k) a0[k] = fmaf(seg[j + k], kv, a0[k]);
            }
        }
        #pragma unroll 1
        for (int d = 1; d <= 28; ++d) {
            const float* rp = lds + (o0 + d) * IPW + ox;
            float seg[32];
            #pragma unroll
            for (int q = 0; q < 8; ++q) *(float4*)(seg + 4 * q) = *(const float4*)(rp + 4 * q);
            const float* kr0 = tk + d * 36;
            const float* kr1 = kr0 - 36;
            #pragma unroll
            for (int j = 0; j < 29; ++j) {
                const float kv0 = kr0[j], kv1 = kr1[j];
                #pragma unroll
                for (int k = 0; k < 4; ++k) {
                    a0[k] = fmaf(seg[j + k], kv0, a0[k]);
                    a1[k] = fmaf(seg[j + k], kv1, a1[k]);
                }
            }
        }
        {
            const float* rp = lds + (o0 + 29) * IPW + ox;
            float seg[32];
            #pragma unroll
            for (int q = 0; q < 8; ++q) *(float4*)(seg + 4 * q) = *(const float4*)(rp + 4 * q);
            const float* kr1 = tk + 28 * 36;
            #pragma unroll
            for (int j = 0; j < 29; ++j) {
                const float kv = kr1[j];
                #pragma unroll
                for (int k = 0; k < 4; ++k) a1[k] = fmaf(seg[j + k], kv, a1[k]);
            }
        }

        const int gbase = c * HW + (by + o0) * W + bx + ox;
        const float* c0p = lds + (o0 + 14) * IPW + ox + 14;
        const float* c1p = c0p + IPW;
        *(float4*)(Apnew + gbase)     = make_float4(a0[0], a0[1], a0[2], a0[3]);
        *(float4*)(Apnew + gbase + W) = make_float4(a1[0], a1[1], a1[2], a1[3]);
        #pragma unroll
        for (int k = 0; k < 4; ++k) S1 += c0p[k] * a0[k] + c1p[k] * a1[k];
    }

    const float tot = block_reduce_256(S1, redbuf);
    if (tid == 0) atomicAdd(ptapI + (bid & (NSLOT - 1)) * SSTR + c, tot);
}

// ---------------- K2: r -= alpha*Ap; x += alpha*p; reduce ||r_new||^2 ----------------
__global__ __launch_bounds__(256) void cgr_k(
    float* __restrict__ r, const float* __restrict__ Ap,
    float* __restrict__ x, const float* __restrict__ p,
    const float* __restrict__ rtrI, const float* __restrict__ ptapI,
    float* __restrict__ rtrNext)
{
    __shared__ float redbuf[4];
    const int c = blockIdx.z;
    const float alpha = sum_slots(rtrI, c) / (sum_slots(ptapI, c) + EPS);
    const int idx = c * HW + (blockIdx.x * 256 + threadIdx.x) * 8;
    float local = 0.f;
    #pragma unroll
    for (int h = 0; h < 2; ++h) {
        const int o = idx + 4 * h;
        float4 rv = *(float4*)(r + o);
        float4 xv = *(float4*)(x + o);
        const float4 av = *(const float4*)(Ap + o);
        const float4 pv = *(const float4*)(p + o);
        rv.x = fmaf(-alpha, av.x, rv.x); xv.x = fmaf(alpha, pv.x, xv.x);
        rv.y = fmaf(-alpha, av.y, rv.y); xv.y = fmaf(alpha, pv.y, xv.y);
        rv.z = fmaf(-alpha, av.z, rv.z); xv.z = fmaf(alpha, pv.z, xv.z);
        rv.w = fmaf(-alpha, av.w, rv.w); xv.w = fmaf(alpha, pv.w, xv.w);
        *(float4*)(r + o) = rv;
        *(float4*)(x + o) = xv;
        local += rv.x * rv.x + rv.y * rv.y + rv.z * rv.z + rv.w * rv.w;
    }
    const float tot = block_reduce_256(local, redbuf);
    if (threadIdx.x == 0)
        atomicAdd(rtrNext + ((int)blockIdx.x & (NSLOT - 1)) * SSTR + c, tot);
}

// ---------------- epilogue: p100 = r100 + beta100*p99 ----------------
__global__ __launch_bounds__(256) void ep_k(
    const float* __restrict__ r100, const float* __restrict__ p99, float* __restrict__ pout,
    const float* __restrict__ rtr99s, const float* __restrict__ rtr100s)
{
    const int c = blockIdx.z;
    const float beta = sum_slots(rtr100s, c) / (sum_slots(rtr99s, c) + EPS);
    const int idx = c * HW + (blockIdx.x * 256 + threadIdx.x) * 8;
    #pragma unroll
    for (int h = 0; h < 2; ++h) {
        const int o = idx + 4 * h;
        const float4 pv = *(const float4*)(p99 + o);
        const float4 rv = *(const float4*)(r100 + o);
        *(float4*)(pout + o) = make_float4(
            fmaf(beta, pv.x, rv.x), fmaf(beta, pv.y, rv.y),
            fmaf(beta, pv.z, rv.z), fmaf(beta, pv.w, rv.w));
    }
}

extern "C" void kernel_launch(void* const* d_in, const int* in_sizes, int n_in,
                              void* d_out, int out_size, void* d_ws, size_t ws_size,
                              hipStream_t stream)
{
    const float* img = (const float*)d_in[0];
    const float* k15 = (const float*)d_in[1];
    const float* rks = (const float*)d_in[2];
    const float* rw  = (const float*)d_in[3];

    float* out = (float*)d_out;
    float* xs = out;            // x (in place)
    float* rs = out + CHW;      // r (in place)
    float* ps = out + 2 * CHW;  // final p_100

    float* ws = (float*)d_ws;
    float* pA   = ws;               // p parity 0
    float* pB   = ws + CHW;         // p parity 1
    float* Ap   = ws + 2 * CHW;
    float* scal = ws + 3 * CHW;
    float* rtrS  = scal;                      // 101 * SCALSZ
    float* ptapS = scal + 101 * SCALSZ;       // 100 * SCALSZ
    float* taps  = scal + 201 * SCALSZ;       // 1688

    float* pbuf[2] = { pA, pB };

    hipMemsetAsync(scal, 0, (size_t)201 * SCALSZ * sizeof(float), stream);
    tap_prep_k<<<1, 256, 0, stream>>>(k15, rks, rw, taps);

    const dim3 bc(256);
    prologue_k<<<dim3(12, 24, 3), bc, 0, stream>>>(img, taps, rs, pA, xs, rtrS);

    for (int i = 0; i < 100; ++i) {
        float* pcur;
        if (i == 0) {
            pcur = pA;
            stepA_k<true><<<dim3(NEDGE + 220, 1, 3), bc, 0, stream>>>(
                pA, rs, taps, Ap, nullptr, rtrS, rtrS, ptapS);
        } else {
            pcur = pbuf[i & 1];
            stepA_k<false><<<dim3(NEDGE + 220, 1, 3), bc, 0, stream>>>(
                pbuf[(i - 1) & 1], rs, taps, Ap, pcur,
                rtrS + (size_t)i * SCALSZ, rtrS + (size_t)(i - 1) * SCALSZ,
                ptapS + (size_t)i * SCALSZ);
        }
        cgr_k<<<dim3(288, 1, 3), bc, 0, stream>>>(
            rs, Ap, xs, pcur,
            rtrS + (size_t)i * SCALSZ, ptapS + (size_t)i * SCALSZ,
            rtrS + (size_t)(i + 1) * SCALSZ);
    }
    // p_99 in pbuf[99 & 1] = pB; r_100 in rs
    ep_k<<<dim3(288, 1, 3), bc, 0, stream>>>(
        rs, pB, ps, rtrS + (size_t)99 * SCALSZ, rtrS + (size_t)100 * SCALSZ);
}

// Round 11
// 8724.442 us; speedup vs baseline: 1.2262x; 1.0013x over previous
//
#include <hip/hip_runtime.h>
#include <hip/hip_cooperative_groups.h>

namespace cg = cooperative_groups;

#define EPS 1e-12f

constexpr int H = 768, W = 768, C = 3;
constexpr int HW = H * W;
constexpr int CHW = C * HW;

constexpr int NSLOT = 16;
constexpr int SSTR = 16;
constexpr int SCALSZ = NSLOT * SSTR;

// prologue (full 64x32 two-pass) geometry
constexpr int SPW = 100, SPH = 60;
constexpr int S0W = 84;
constexpr int S1W = 76, S1H = 36;
constexpr int UBUF = SPH * SPW;

// edge strips: 64x16 output, two-pass
constexpr int ESPH = 44;
constexpr int ES1H = 20;
constexpr int ELDS = ESPH * SPW + 2 * ES1H * S1W;  // 7440 floats (29.8 KB)
// interior: composed 29x29 on 64x32
constexpr int IPW = 92, IPH = 60;                  // 5520 floats
constexpr int NEDGE3 = 408;                        // 136 strips x 3 ch
constexpr int NGRID = 1068;                        // 408 + 660 interior
constexpr int NB_B = 864;                          // phase-B blocks (288/ch)

__device__ __forceinline__ float block_reduce_256(float v, float* redbuf) {
    #pragma unroll
    for (int off = 32; off > 0; off >>= 1) v += __shfl_down(v, off, 64);
    const int tid = threadIdx.x;
    if ((tid & 63) == 0) redbuf[tid >> 6] = v;
    __syncthreads();
    return redbuf[0] + redbuf[1] + redbuf[2] + redbuf[3];
}

__device__ __forceinline__ float sum_slots(const float* base, int c) {
    float s = 0.f;
    #pragma unroll
    for (int k = 0; k < NSLOT; ++k) s += base[k * SSTR + c];
    return s;
}

// taps: [0..239] k15 fwd (15x16), [240..479] k15 flip, [480..559] rk fwd (2x5x8),
// [560..639] rk flip, [640..1683] TK 29x36 composed, [1684] w0^2, [1685] w1^2
__global__ void tap_prep_k(const float* __restrict__ k15, const float* __restrict__ rks,
                           const float* __restrict__ rw, float* __restrict__ taps) {
    const int tid = threadIdx.x;
    if (tid < 240) {
        const int i = tid >> 4, j = tid & 15;
        taps[tid]       = (j < 15) ? k15[i * 15 + j] : 0.f;
        taps[240 + tid] = (j < 15) ? k15[(14 - i) * 15 + (14 - j)] : 0.f;
    }
    if (tid < 80) {
        const int kk = tid / 40, rem = tid % 40, i = rem >> 3, j = rem & 7;
        taps[480 + tid] = (j < 5) ? rks[kk * 25 + i * 5 + j] : 0.f;
        taps[560 + tid] = (j < 5) ? rks[kk * 25 + (4 - i) * 5 + (4 - j)] : 0.f;
    }
    const float w20 = rw[0] * rw[0], w21 = rw[1] * rw[1];
    if (tid == 0) { taps[1684] = w20; taps[1685] = w21; }
    for (int t = tid; t < 29 * 36; t += 256) {
        const int uy = t / 36, ux = t - uy * 36;
        float s = 0.f;
        if (ux < 29) {
            const int dy = uy - 14, dx = ux - 14;
            for (int sy = 0; sy < 15; ++sy) {
                const int ty = sy + dy;
                if ((unsigned)ty >= 15u) continue;
                for (int sx = 0; sx < 15; ++sx) {
                    const int tx = sx + dx;
                    if ((unsigned)tx < 15u) s += k15[sy * 15 + sx] * k15[ty * 15 + tx];
                }
            }
            if (dy >= -4 && dy <= 4 && dx >= -4 && dx <= 4) {
                float q0 = 0.f, q1 = 0.f;
                for (int sy = 0; sy < 5; ++sy) {
                    const int ty = sy + dy;
                    if ((unsigned)ty >= 5u) continue;
                    for (int sx = 0; sx < 5; ++sx) {
                        const int tx = sx + dx;
                        if ((unsigned)tx >= 5u) continue;
                        q0 += rks[sy * 5 + sx] * rks[ty * 5 + tx];
                        q1 += rks[25 + sy * 5 + sx] * rks[25 + ty * 5 + tx];
                    }
                }
                s += w20 * q0 + w21 * q1;
            }
        }
        taps[640 + t] = s;
    }
}

// ---------------- prologue: r0 = K^T b - A(img); p0 = r0; x0 = img; rtr0 ----------------
__global__ __launch_bounds__(256) void prologue_k(
    const float* __restrict__ img, const float* __restrict__ taps,
    float* __restrict__ outR, float* __restrict__ outP, float* __restrict__ outX,
    float* __restrict__ red)
{
    __shared__ __align__(16) float ub[UBUF];
    __shared__ __align__(16) float st1[S1H * S1W];
    __shared__ __align__(16) float st2[S1H * S1W];
    __shared__ float redbuf[4];

    const float* kt   = taps;
    const float* ktf  = taps + 240;
    const float* rkt  = taps + 480;
    const float* rktf = taps + 560;
    const float w02 = taps[1684], w12 = taps[1685];

    const int c = blockIdx.z;
    const int bx = blockIdx.x * 64, by = blockIdx.y * 32;
    const int tid = threadIdx.x;
    const float* inC = img + c * HW;

    for (int t = tid; t < SPH * 96; t += 256) {
        const int ly = t / 96, lx = t - ly * 96;
        const int gy = by - 14 + ly, gx = bx - 14 + lx;
        float v = 0.f;
        if ((unsigned)gy < (unsigned)H && (unsigned)gx < (unsigned)W) v = inC[gy * W + gx];
        ub[ly * SPW + lx] = v;
    }
    __syncthreads();

    const int oy = tid >> 3;
    const int ox = (tid & 7) << 3;

    // phase 1b
    {
        const int s0 = tid, s1i = tid + 256;
        const int row0 = s0 / 9, c0 = (s0 - row0 * 9) << 3;
        const int row1 = s1i / 9, c1 = (s1i - row1 * 9) << 3;
        const bool v1 = (s1i < 324);
        float b0[8], c0a[8], b1[8], c1a[8];
        #pragma unroll
        for (int k = 0; k < 8; ++k) { b0[k] = 0.f; c0a[k] = 0.f; b1[k] = 0.f; c1a[k] = 0.f; }
        #pragma unroll 1
        for (int i = 0; i < 5; ++i) {
            float kb[8], kc[8];
            #pragma unroll
            for (int q = 0; q < 2; ++q) {
                *(float4*)(kb + 4 * q) = *(const float4*)(rkt + i * 8 + 4 * q);
                *(float4*)(kc + 4 * q) = *(const float4*)(rkt + 40 + i * 8 + 4 * q);
            }
            {
                const float* rp = ub + (row0 + 10 + i) * SPW + c0 + 8;
                float seg[16];
                #pragma unroll
                for (int q = 0; q < 4; ++q) *(float4*)(seg + 4 * q) = *(const float4*)(rp + 4 * q);
                #pragma unroll
                for (int j = 0; j < 5; ++j)
                    #pragma unroll
                    for (int k = 0; k < 8; ++k) {
                        b0[k]  = fmaf(seg[j + k + 2], kb[j], b0[k]);
                        c0a[k] = fmaf(seg[j + k + 2], kc[j], c0a[k]);
                    }
            }
            if (v1) {
                const float* rp = ub + (row1 + 10 + i) * SPW + c1 + 8;
                float seg[16];
                #pragma unroll
                for (int q = 0; q < 4; ++q) *(float4*)(seg + 4 * q) = *(const float4*)(rp + 4 * q);
                #pragma unroll
                for (int j = 0; j < 5; ++j)
                    #pragma unroll
                    for (int k = 0; k < 8; ++k) {
                        b1[k]  = fmaf(seg[j + k + 2], kb[j], b1[k]);
                        c1a[k] = fmaf(seg[j + k + 2], kc[j], c1a[k]);
                    }
            }
        }
        {
            const int gy = by - 2 + row0, gxb = bx - 2 + c0;
            #pragma unroll
            for (int k = 0; k < 8; ++k)
                if (((unsigned)gy >= (unsigned)H) || ((unsigned)(gxb + k) >= (unsigned)W)) { b0[k] = 0.f; c0a[k] = 0.f; }
            float* o1 = st1 + row0 * S1W + c0;
            float* o2 = st2 + row0 * S1W + c0;
            *(float4*)(o1) = make_float4(b0[0], b0[1], b0[2], b0[3]);
            *(float4*)(o1 + 4) = make_float4(b0[4], b0[5], b0[6], b0[7]);
            *(float4*)(o2) = make_float4(c0a[0], c0a[1], c0a[2], c0a[3]);
            *(float4*)(o2 + 4) = make_float4(c0a[4], c0a[5], c0a[6], c0a[7]);
        }
        if (v1) {
            const int gy = by - 2 + row1, gxb = bx - 2 + c1;
            #pragma unroll
            for (int k = 0; k < 8; ++k)
                if (((unsigned)gy >= (unsigned)H) || ((unsigned)(gxb + k) >= (unsigned)W)) { b1[k] = 0.f; c1a[k] = 0.f; }
            float* o1 = st1 + row1 * S1W + c1;
            float* o2 = st2 + row1 * S1W + c1;
            *(float4*)(o1) = make_float4(b1[0], b1[1], b1[2], b1[3]);
            *(float4*)(o1 + 4) = make_float4(b1[4], b1[5], b1[6], b1[7]);
            *(float4*)(o2) = make_float4(c1a[0], c1a[1], c1a[2], c1a[3]);
            *(float4*)(o2 + 4) = make_float4(c1a[4], c1a[5], c1a[6], c1a[7]);
        }
    }

    float pctr[8];
    {
        const float* ctr = ub + (oy + 14) * SPW + ox + 14;
        #pragma unroll
        for (int k = 0; k < 8; ++k) pctr[k] = ctr[k];
    }

    float vimg[8];
    #pragma unroll
    for (int k = 0; k < 8; ++k) vimg[k] = 0.f;
    #pragma unroll 1
    for (int i = 0; i < 15; ++i) {
        const float* rowp = ub + (oy + 7 + i) * SPW + ox + 4;
        float seg[28];
        #pragma unroll
        for (int q = 0; q < 7; ++q) *(float4*)(seg + 4 * q) = *(const float4*)(rowp + 4 * q);
        float kv[16];
        #pragma unroll
        for (int q = 0; q < 4; ++q) *(float4*)(kv + 4 * q) = *(const float4*)(ktf + i * 16 + 4 * q);
        #pragma unroll
        for (int j = 0; j < 15; ++j)
            #pragma unroll
            for (int k = 0; k < 8; ++k) vimg[k] = fmaf(seg[j + k + 3], kv[j], vimg[k]);
    }

    const int s0 = tid, s1i = tid + 256;
    const int row0 = s0 / 10, ca0 = (s0 - row0 * 10) << 3;
    const int row1 = s1i / 10, ca1 = (s1i - row1 * 10) << 3;
    const bool av1 = (s1i < 460);
    float a0[8], a1[8];
    #pragma unroll
    for (int k = 0; k < 8; ++k) { a0[k] = 0.f; a1[k] = 0.f; }
    #pragma unroll 1
    for (int i = 0; i < 15; ++i) {
        float kv[16];
        #pragma unroll
        for (int q = 0; q < 4; ++q) *(float4*)(kv + 4 * q) = *(const float4*)(kt + i * 16 + 4 * q);
        {
            const float* rp = ub + (row0 + i) * SPW + ca0;
            float seg[24];
            #pragma unroll
            for (int q = 0; q < 6; ++q) *(float4*)(seg + 4 * q) = *(const float4*)(rp + 4 * q);
            #pragma unroll
            for (int j = 0; j < 15; ++j)
                #pragma unroll
                for (int k = 0; k < 8; ++k) a0[k] = fmaf(seg[j + k], kv[j], a0[k]);
        }
        if (av1) {
            const float* rp = ub + (row1 + i) * SPW + ca1;
            float seg[24];
            #pragma unroll
            for (int q = 0; q < 6; ++q) *(float4*)(seg + 4 * q) = *(const float4*)(rp + 4 * q);
            #pragma unroll
            for (int j = 0; j < 15; ++j)
                #pragma unroll
                for (int k = 0; k < 8; ++k) a1[k] = fmaf(seg[j + k], kv[j], a1[k]);
        }
    }
    {
        const int gy = by - 7 + row0, gxb = bx - 7 + ca0;
        #pragma unroll
        for (int k = 0; k < 8; ++k)
            if (((unsigned)gy >= (unsigned)H) || ((unsigned)(gxb + k) >= (unsigned)W)) a0[k] = 0.f;
    }
    if (av1) {
        const int gy = by - 7 + row1, gxb = bx - 7 + ca1;
        #pragma unroll
        for (int k = 0; k < 8; ++k)
            if (((unsigned)gy >= (unsigned)H) || ((unsigned)(gxb + k) >= (unsigned)W)) a1[k] = 0.f;
    }
    __syncthreads();
    {
        float* o = ub + row0 * S0W + ca0;
        *(float4*)(o) = make_float4(a0[0], a0[1], a0[2], a0[3]);
        *(float4*)(o + 4) = make_float4(a0[4], a0[5], a0[6], a0[7]);
    }
    if (av1) {
        float* o = ub + row1 * S0W + ca1;
        *(float4*)(o) = make_float4(a1[0], a1[1], a1[2], a1[3]);
        *(float4*)(o + 4) = make_float4(a1[4], a1[5], a1[6], a1[7]);
    }
    __syncthreads();

    float acc[8];
    #pragma unroll
    for (int k = 0; k < 8; ++k) acc[k] = 0.f;
    #pragma unroll 1
    for (int i = 0; i < 15; ++i) {
        float kv[16];
        #pragma unroll
        for (int q = 0; q < 4; ++q) *(float4*)(kv + 4 * q) = *(const float4*)(ktf + i * 16 + 4 * q);
        const float* rp = ub + (oy + i) * S0W + ox;
        float seg[24];
        #pragma unroll
        for (int q = 0; q < 6; ++q) *(float4*)(seg + 4 * q) = *(const float4*)(rp + 4 * q);
        #pragma unroll
        for (int j = 0; j < 15; ++j)
            #pragma unroll
            for (int k = 0; k < 8; ++k) acc[k] = fmaf(seg[j + k], kv[j], acc[k]);
    }
    float accB[8], accC[8];
    #pragma unroll
    for (int k = 0; k < 8; ++k) { accB[k] = 0.f; accC[k] = 0.f; }
    #pragma unroll 1
    for (int i = 0; i < 5; ++i) {
        float kb[8], kc[8];
        #pragma unroll
        for (int q = 0; q < 2; ++q) {
            *(float4*)(kb + 4 * q) = *(const float4*)(rktf + i * 8 + 4 * q);
            *(float4*)(kc + 4 * q) = *(const float4*)(rktf + 40 + i * 8 + 4 * q);
        }
        const float* r1p = st1 + (oy + i) * S1W + ox;
        const float* r2p = st2 + (oy + i) * S1W + ox;
        float sA[12], sB[12];
        #pragma unroll
        for (int q = 0; q < 3; ++q) *(float4*)(sA + 4 * q) = *(const float4*)(r1p + 4 * q);
        #pragma unroll
        for (int q = 0; q < 3; ++q) *(float4*)(sB + 4 * q) = *(const float4*)(r2p + 4 * q);
        #pragma unroll
        for (int j = 0; j < 5; ++j)
            #pragma unroll
            for (int k = 0; k < 8; ++k) {
                accB[k] = fmaf(sA[j + k], kb[j], accB[k]);
                accC[k] = fmaf(sB[j + k], kc[j], accC[k]);
            }
    }

    float v[8];
    #pragma unroll
    for (int k = 0; k < 8; ++k) v[k] = vimg[k] - (acc[k] + w02 * accB[k] + w12 * accC[k]);

    const int g = c * HW + (by + oy) * W + bx + ox;
    *(float4*)(outR + g)     = make_float4(v[0], v[1], v[2], v[3]);
    *(float4*)(outR + g + 4) = make_float4(v[4], v[5], v[6], v[7]);
    *(float4*)(outP + g)     = make_float4(v[0], v[1], v[2], v[3]);
    *(float4*)(outP + g + 4) = make_float4(v[4], v[5], v[6], v[7]);
    *(float4*)(outX + g)     = make_float4(pctr[0], pctr[1], pctr[2], pctr[3]);
    *(float4*)(outX + g + 4) = make_float4(pctr[4], pctr[5], pctr[6], pctr[7]);
    float local = 0.f;
    #pragma unroll
    for (int k = 0; k < 8; ++k) local += v[k] * v[k];
    const float tot = block_reduce_256(local, redbuf);
    if (tid == 0) {
        const int bid = blockIdx.y * gridDim.x + blockIdx.x;
        atomicAdd(red + (bid & (NSLOT - 1)) * SSTR + c, tot);
    }
}

// ================= shared phase bodies (used by coop kernel AND fallback kernels) =================

__device__ __forceinline__ void phaseA_body(
    int bid, int tid, float* lds, float* redbuf, bool first,
    const float* __restrict__ pold, const float* __restrict__ rvec, float* __restrict__ pnew,
    const float* __restrict__ taps, float* __restrict__ Ap,
    const float* __restrict__ rtrI, const float* __restrict__ rtrIm1, float* __restrict__ ptapI)
{
    const bool is_edge = (bid < NEDGE3);
    int c, rb;
    if (is_edge) { c = bid % 3; rb = bid / 3; }
    else { const int v = bid - NEDGE3; c = v % 3; rb = v / 3; }

    float beta = 0.f;
    if (!first) beta = sum_slots(rtrI, c) / (sum_slots(rtrIm1, c) + EPS);

    float S1 = 0.f;

    if (is_edge) {
        // ============ EDGE role: 64x16 strip, two-pass (exact boundaries) ============
        float* ub  = lds;
        float* st1 = lds + ESPH * SPW;
        float* st2 = st1 + ES1H * S1W;
        const float* kt   = taps;
        const float* ktf  = taps + 240;
        const float* rkt  = taps + 480;
        const float* rktf = taps + 560;
        const float w02 = taps[1684], w12 = taps[1685];

        const int e = rb >> 1, half = rb & 1;
        int tbx, tby;
        { if (e < 12)      { tbx = e;      tby = 0; }
          else if (e < 24) { tbx = e - 12; tby = 23; }
          else if (e < 46) { tbx = 0;      tby = 1 + (e - 24); }
          else             { tbx = 11;     tby = 1 + (e - 46); } }
        const int bx = tbx * 64, by = tby * 32 + half * 16;

        for (int s = tid; s < ESPH * 96; s += 256) {
            const int ly = s / 96, lx = s - ly * 96;
            const int gy = by - 14 + ly, gx = bx - 14 + lx;
            float pe = 0.f;
            if ((unsigned)gy < (unsigned)H && (unsigned)gx < (unsigned)W) {
                const int g = c * HW + gy * W + gx;
                const float pv = pold[g];
                if (first) pe = pv;
                else {
                    pe = fmaf(beta, pv, rvec[g]);
                    if (ly >= 14 && ly < 30 && lx >= 14 && lx < 78) pnew[g] = pe;
                }
            }
            ub[ly * SPW + lx] = pe;
        }
        __syncthreads();

        const int oy2 = tid >> 4;
        const int ox2 = (tid & 15) << 2;

        // phase 1b
        {
            const int row0 = tid / 9, c0 = (tid - (tid / 9) * 9) << 3;
            if (tid < 180) {
                float b0[8], c0a[8];
                #pragma unroll
                for (int k = 0; k < 8; ++k) { b0[k] = 0.f; c0a[k] = 0.f; }
                #pragma unroll 1
                for (int ii = 0; ii < 5; ++ii) {
                    float kb[8], kc[8];
                    #pragma unroll
                    for (int q = 0; q < 2; ++q) {
                        *(float4*)(kb + 4 * q) = *(const float4*)(rkt + ii * 8 + 4 * q);
                        *(float4*)(kc + 4 * q) = *(const float4*)(rkt + 40 + ii * 8 + 4 * q);
                    }
                    const float* rp = ub + (row0 + 10 + ii) * SPW + c0 + 8;
                    float seg[16];
                    #pragma unroll
                    for (int q = 0; q < 4; ++q) *(float4*)(seg + 4 * q) = *(const float4*)(rp + 4 * q);
                    #pragma unroll
                    for (int j = 0; j < 5; ++j)
                        #pragma unroll
                        for (int k = 0; k < 8; ++k) {
                            b0[k]  = fmaf(seg[j + k + 2], kb[j], b0[k]);
                            c0a[k] = fmaf(seg[j + k + 2], kc[j], c0a[k]);
                        }
                }
                const int gy = by - 2 + row0, gxb = bx - 2 + c0;
                #pragma unroll
                for (int k = 0; k < 8; ++k)
                    if (((unsigned)gy >= (unsigned)H) || ((unsigned)(gxb + k) >= (unsigned)W)) { b0[k] = 0.f; c0a[k] = 0.f; }
                float* o1 = st1 + row0 * S1W + c0;
                float* o2 = st2 + row0 * S1W + c0;
                *(float4*)(o1) = make_float4(b0[0], b0[1], b0[2], b0[3]);
                *(float4*)(o1 + 4) = make_float4(b0[4], b0[5], b0[6], b0[7]);
                *(float4*)(o2) = make_float4(c0a[0], c0a[1], c0a[2], c0a[3]);
                *(float4*)(o2 + 4) = make_float4(c0a[4], c0a[5], c0a[6], c0a[7]);
            }
        }

        float pctr[4];
        {
            const float* ctr = ub + (oy2 + 14) * SPW + ox2 + 14;
            #pragma unroll
            for (int k = 0; k < 4; ++k) pctr[k] = ctr[k];
        }

        // phase 1a
        const int s0 = tid, s1i = tid + 256;
        const int row0 = s0 / 10, ca0 = (s0 - row0 * 10) << 3;
        const int row1 = s1i / 10, ca1 = (s1i - row1 * 10) << 3;
        const bool av1 = (s1i < 300);
        float a0[8], a1[8];
        #pragma unroll
        for (int k = 0; k < 8; ++k) { a0[k] = 0.f; a1[k] = 0.f; }
        #pragma unroll 1
        for (int ii = 0; ii < 15; ++ii) {
            float kv[16];
            #pragma unroll
            for (int q = 0; q < 4; ++q) *(float4*)(kv + 4 * q) = *(const float4*)(kt + ii * 16 + 4 * q);
            {
                const float* rp = ub + (row0 + ii) * SPW + ca0;
                float seg[24];
                #pragma unroll
                for (int q = 0; q < 6; ++q) *(float4*)(seg + 4 * q) = *(const float4*)(rp + 4 * q);
                #pragma unroll
                for (int j = 0; j < 15; ++j)
                    #pragma unroll
                    for (int k = 0; k < 8; ++k) a0[k] = fmaf(seg[j + k], kv[j], a0[k]);
            }
            if (av1) {
                const float* rp = ub + (row1 + ii) * SPW + ca1;
                float seg[24];
                #pragma unroll
                for (int q = 0; q < 6; ++q) *(float4*)(seg + 4 * q) = *(const float4*)(rp + 4 * q);
                #pragma unroll
                for (int j = 0; j < 15; ++j)
                    #pragma unroll
                    for (int k = 0; k < 8; ++k) a1[k] = fmaf(seg[j + k], kv[j], a1[k]);
            }
        }
        {
            const int gy = by - 7 + row0, gxb = bx - 7 + ca0;
            #pragma unroll
            for (int k = 0; k < 8; ++k)
                if (((unsigned)gy >= (unsigned)H) || ((unsigned)(gxb + k) >= (unsigned)W)) a0[k] = 0.f;
        }
        if (av1) {
            const int gy = by - 7 + row1, gxb = bx - 7 + ca1;
            #pragma unroll
            for (int k = 0; k < 8; ++k)
                if (((unsigned)gy >= (unsigned)H) || ((unsigned)(gxb + k) >= (unsigned)W)) a1[k] = 0.f;
        }
        __syncthreads();
        {
            float* o = ub + row0 * S0W + ca0;
            *(float4*)(o) = make_float4(a0[0], a0[1], a0[2], a0[3]);
            *(float4*)(o + 4) = make_float4(a0[4], a0[5], a0[6], a0[7]);
        }
        if (av1) {
            float* o = ub + row1 * S0W + ca1;
            *(float4*)(o) = make_float4(a1[0], a1[1], a1[2], a1[3]);
            *(float4*)(o + 4) = make_float4(a1[4], a1[5], a1[6], a1[7]);
        }
        __syncthreads();

        // phase 2
        float acc[4];
        #pragma unroll
        for (int k = 0; k < 4; ++k) acc[k] = 0.f;
        #pragma unroll 1
        for (int ii = 0; ii < 15; ++ii) {
            float kv[16];
            #pragma unroll
            for (int q = 0; q < 4; ++q) *(float4*)(kv + 4 * q) = *(const float4*)(ktf + ii * 16 + 4 * q);
            const float* rp = ub + (oy2 + ii) * S0W + ox2;
            float seg[20];
            #pragma unroll
            for (int q = 0; q < 5; ++q) *(float4*)(seg + 4 * q) = *(const float4*)(rp + 4 * q);
            #pragma unroll
            for (int j = 0; j < 15; ++j)
                #pragma unroll
                for (int k = 0; k < 4; ++k) acc[k] = fmaf(seg[j + k], kv[j], acc[k]);
        }
        float accB[4], accC[4];
        #pragma unroll
        for (int k = 0; k < 4; ++k) { accB[k] = 0.f; accC[k] = 0.f; }
        #pragma unroll 1
        for (int ii = 0; ii < 5; ++ii) {
            float kb[8], kc[8];
            #pragma unroll
            for (int q = 0; q < 2; ++q) {
                *(float4*)(kb + 4 * q) = *(const float4*)(rktf + ii * 8 + 4 * q);
                *(float4*)(kc + 4 * q) = *(const float4*)(rktf + 40 + ii * 8 + 4 * q);
            }
            const float* r1p = st1 + (oy2 + ii) * S1W + ox2;
            const float* r2p = st2 + (oy2 + ii) * S1W + ox2;
            float sA[8], sB[8];
            #pragma unroll
            for (int q = 0; q < 2; ++q) *(float4*)(sA + 4 * q) = *(const float4*)(r1p + 4 * q);
            #pragma unroll
            for (int q = 0; q < 2; ++q) *(float4*)(sB + 4 * q) = *(const float4*)(r2p + 4 * q);
            #pragma unroll
            for (int j = 0; j < 5; ++j)
                #pragma unroll
                for (int k = 0; k < 4; ++k) {
                    accB[k] = fmaf(sA[j + k], kb[j], accB[k]);
                    accC[k] = fmaf(sB[j + k], kc[j], accC[k]);
                }
        }

        float v[4];
        #pragma unroll
        for (int k = 0; k < 4; ++k) v[k] = acc[k] + w02 * accB[k] + w12 * accC[k];

        const int g = c * HW + (by + oy2) * W + bx + ox2;
        *(float4*)(Ap + g) = make_float4(v[0], v[1], v[2], v[3]);
        #pragma unroll
        for (int k = 0; k < 4; ++k) S1 += pctr[k] * v[k];
    } else {
        // ============ INTERIOR role: composed 29x29 on 64x32 ============
        const float* tk = taps + 640;
        const int bx = 64 + (rb % 10) * 64, by = 32 + (rb / 10) * 32;
        const int gy0 = by - 14, gx0 = bx - 14;

        for (int s = tid; s < IPH * IPW; s += 256) {
            const int ly = s / IPW, lx = s - ly * IPW;
            const int g = c * HW + (gy0 + ly) * W + (gx0 + lx);
            const float pv = pold[g];
            float pe;
            if (first) pe = pv;
            else {
                pe = fmaf(beta, pv, rvec[g]);
                if (ly >= 14 && ly < 46 && lx >= 14 && lx < 78) pnew[g] = pe;
            }
            lds[s] = pe;
        }
        __syncthreads();

        const int ox = (tid & 15) << 2;
        const int o0 = (tid >> 4) << 1;

        float a0[4], a1[4];
        #pragma unroll
        for (int k = 0; k < 4; ++k) { a0[k] = 0.f; a1[k] = 0.f; }
        {
            const float* rp = lds + o0 * IPW + ox;
            float seg[32];
            #pragma unroll
            for (int q = 0; q < 8; ++q) *(float4*)(seg + 4 * q) = *(const float4*)(rp + 4 * q);
            #pragma unroll
            for (int j = 0; j < 29; ++j) {
                const float kv = tk[j];
                #pragma unroll
                for (int k = 0; k < 4; ++k) a0[k] = fmaf(seg[j + k], kv, a0[k]);
            }
        }
        #pragma unroll 1
        for (int d = 1; d <= 28; ++d) {
            const float* rp = lds + (o0 + d) * IPW + ox;
            float seg[32];
            #pragma unroll
            for (int q = 0; q < 8; ++q) *(float4*)(seg + 4 * q) = *(const float4*)(rp + 4 * q);
            const float* kr0 = tk + d * 36;
            const float* kr1 = kr0 - 36;
            #pragma unroll
            for (int j = 0; j < 29; ++j) {
                const float kv0 = kr0[j], kv1 = kr1[j];
                #pragma unroll
                for (int k = 0; k < 4; ++k) {
                    a0[k] = fmaf(seg[j + k], kv0, a0[k]);
                    a1[k] = fmaf(seg[j + k], kv1, a1[k]);
                }
            }
        }
        {
            const float* rp = lds + (o0 + 29) * IPW + ox;
            float seg[32];
            #pragma unroll
            for (int q = 0; q < 8; ++q) *(float4*)(seg + 4 * q) = *(const float4*)(rp + 4 * q);
            const float* kr1 = tk + 28 * 36;
            #pragma unroll
            for (int j = 0; j < 29; ++j) {
                const float kv = kr1[j];
                #pragma unroll
                for (int k = 0; k < 4; ++k) a1[k] = fmaf(seg[j + k], kv, a1[k]);
            }
        }

        const int gbase = c * HW + (by + o0) * W + bx + ox;
        const float* c0p = lds + (o0 + 14) * IPW + ox + 14;
        const float* c1p = c0p + IPW;
        *(float4*)(Ap + gbase)     = make_float4(a0[0], a0[1], a0[2], a0[3]);
        *(float4*)(Ap + gbase + W) = make_float4(a1[0], a1[1], a1[2], a1[3]);
        #pragma unroll
        for (int k = 0; k < 4; ++k) S1 += c0p[k] * a0[k] + c1p[k] * a1[k];
    }

    const float tot = block_reduce_256(S1, redbuf);
    if (tid == 0) atomicAdd(ptapI + (bid & (NSLOT - 1)) * SSTR + c, tot);
}

__device__ __forceinline__ void phaseB_body(
    int bid, int tid, float* redbuf,
    float* __restrict__ r, float* __restrict__ x,
    const float* __restrict__ Ap, const float* __restrict__ pc,
    const float* __restrict__ rtrI, const float* __restrict__ ptapI,
    float* __restrict__ rtrNext)
{
    const int c3 = bid / 288;
    const float alpha = sum_slots(rtrI, c3) / (sum_slots(ptapI, c3) + EPS);
    const int o = (bid * 256 + tid) * 8;
    float local = 0.f;
    #pragma unroll
    for (int h = 0; h < 2; ++h) {
        const int oo = o + 4 * h;
        float4 rv = *(float4*)(r + oo);
        float4 xv = *(float4*)(x + oo);
        const float4 av = *(const float4*)(Ap + oo);
        const float4 pv = *(const float4*)(pc + oo);
        rv.x = fmaf(-alpha, av.x, rv.x); xv.x = fmaf(alpha, pv.x, xv.x);
        rv.y = fmaf(-alpha, av.y, rv.y); xv.y = fmaf(alpha, pv.y, xv.y);
        rv.z = fmaf(-alpha, av.z, rv.z); xv.z = fmaf(alpha, pv.z, xv.z);
        rv.w = fmaf(-alpha, av.w, rv.w); xv.w = fmaf(alpha, pv.w, xv.w);
        *(float4*)(r + oo) = rv;
        *(float4*)(x + oo) = xv;
        local += rv.x * rv.x + rv.y * rv.y + rv.z * rv.z + rv.w * rv.w;
    }
    const float tot = block_reduce_256(local, redbuf);
    if (tid == 0)
        atomicAdd(rtrNext + (bid & (NSLOT - 1)) * SSTR + c3, tot);
}

__device__ __forceinline__ void epilogue_body(
    int bid, int tid,
    const float* __restrict__ r100, const float* __restrict__ p99, float* __restrict__ pout,
    const float* __restrict__ rtr99s, const float* __restrict__ rtr100s)
{
    const int c3 = bid / 288;
    const float beta = sum_slots(rtr100s, c3) / (sum_slots(rtr99s, c3) + EPS);
    const int o = (bid * 256 + tid) * 8;
    #pragma unroll
    for (int h = 0; h < 2; ++h) {
        const int oo = o + 4 * h;
        const float4 pv = *(const float4*)(p99 + oo);
        const float4 rv = *(const float4*)(r100 + oo);
        *(float4*)(pout + oo) = make_float4(
            fmaf(beta, pv.x, rv.x), fmaf(beta, pv.y, rv.y),
            fmaf(beta, pv.z, rv.z), fmaf(beta, pv.w, rv.w));
    }
}

// ================= cooperative kernel: 100 iterations, grid-synced =================
__global__ __launch_bounds__(256, 5) void cg_coop_k(
    float* r, float* x, float* pA, float* pB, float* Ap,
    const float* taps, float* rtrS, float* ptapS, float* pout)
{
    cg::grid_group grid = cg::this_grid();
    __shared__ __align__(16) float lds[ELDS];
    __shared__ float redbuf[4];
    const int bid = blockIdx.x;
    const int tid = threadIdx.x;

    for (int i = 0; i < 100; ++i) {
        const bool first = (i == 0);
        const float* rtrI = rtrS + (size_t)i * SCALSZ;
        float* ptapI = ptapS + (size_t)i * SCALSZ;
        const float* pold = first ? pA : ((i & 1) ? pA : pB);
        float* pnew = (i & 1) ? pB : pA;

        phaseA_body(bid, tid, lds, redbuf, first, pold, r, pnew, taps, Ap,
                    rtrI, rtrI - SCALSZ, ptapI);
        grid.sync();
        if (bid < NB_B)
            phaseB_body(bid, tid, redbuf, r, x, Ap, first ? pA : pnew,
                        rtrI, ptapI, rtrS + (size_t)(i + 1) * SCALSZ);
        grid.sync();
    }
    if (bid < NB_B)
        epilogue_body(bid, tid, r, pB, pout,
                      rtrS + (size_t)99 * SCALSZ, rtrS + (size_t)100 * SCALSZ);
}

// ================= fallback standalone kernels (round-9 path) =================
__global__ __launch_bounds__(256) void stepA_sk(
    int first, const float* pold, const float* rvec, float* pnew,
    const float* taps, float* Ap,
    const float* rtrI, const float* rtrIm1, float* ptapI)
{
    __shared__ __align__(16) float lds[ELDS];
    __shared__ float redbuf[4];
    phaseA_body(blockIdx.x, threadIdx.x, lds, redbuf, first != 0,
                pold, rvec, pnew, taps, Ap, rtrI, rtrIm1, ptapI);
}

__global__ __launch_bounds__(256) void cgr_sk(
    float* r, float* x, const float* Ap, const float* pc,
    const float* rtrI, const float* ptapI, float* rtrNext)
{
    __shared__ float redbuf[4];
    phaseB_body(blockIdx.x, threadIdx.x, redbuf, r, x, Ap, pc, rtrI, ptapI, rtrNext);
}

__global__ __launch_bounds__(256) void ep_sk(
    const float* r100, const float* p99, float* pout,
    const float* rtr99s, const float* rtr100s)
{
    epilogue_body(blockIdx.x, threadIdx.x, r100, p99, pout, rtr99s, rtr100s);
}

extern "C" void kernel_launch(void* const* d_in, const int* in_sizes, int n_in,
                              void* d_out, int out_size, void* d_ws, size_t ws_size,
                              hipStream_t stream)
{
    const float* img = (const float*)d_in[0];
    const float* k15 = (const float*)d_in[1];
    const float* rks = (const float*)d_in[2];
    const float* rw  = (const float*)d_in[3];

    float* out = (float*)d_out;
    float* xs = out;            // x (in place)
    float* rs = out + CHW;      // r (in place)
    float* ps = out + 2 * CHW;  // final p_100

    float* ws = (float*)d_ws;
    float* pA   = ws;               // p parity 0
    float* pB   = ws + CHW;         // p parity 1
    float* Ap   = ws + 2 * CHW;
    float* scal = ws + 3 * CHW;
    float* rtrS  = scal;                      // 101 * SCALSZ
    float* ptapS = scal + 101 * SCALSZ;       // 100 * SCALSZ
    float* taps  = scal + 201 * SCALSZ;       // 1688

    hipMemsetAsync(scal, 0, (size_t)201 * SCALSZ * sizeof(float), stream);
    tap_prep_k<<<1, 256, 0, stream>>>(k15, rks, rw, taps);

    const dim3 bc(256);
    prologue_k<<<dim3(12, 24, 3), bc, 0, stream>>>(img, taps, rs, pA, xs, rtrS);

    // deterministic host-side decision: cooperative only if co-residency is guaranteed
    int maxb = 0;
    (void)hipOccupancyMaxActiveBlocksPerMultiprocessor(&maxb, cg_coop_k, 256, 0);
    const bool coop_ok = (maxb * 256 >= NGRID);

    if (coop_ok) {
        void* kargs[] = { (void*)&rs, (void*)&xs, (void*)&pA, (void*)&pB, (void*)&Ap,
                          (void*)&taps, (void*)&rtrS, (void*)&ptapS, (void*)&ps };
        hipLaunchCooperativeKernel((const void*)cg_coop_k, dim3(NGRID), bc, kargs, 0, stream);
    } else {
        float* pbuf[2] = { pA, pB };
        for (int i = 0; i < 100; ++i) {
            const float* rtrI = rtrS + (size_t)i * SCALSZ;
            float* ptapI = ptapS + (size_t)i * SCALSZ;
            float* pcur;
            if (i == 0) {
                pcur = pA;
                stepA_sk<<<dim3(NGRID), bc, 0, stream>>>(
                    1, pA, rs, nullptr, taps, Ap, rtrI, rtrI, ptapI);
            } else {
                pcur = pbuf[i & 1];
                stepA_sk<<<dim3(NGRID), bc, 0, stream>>>(
                    0, pbuf[(i - 1) & 1], rs, pcur, taps, Ap,
                    rtrI, rtrS + (size_t)(i - 1) * SCALSZ, ptapI);
            }
            cgr_sk<<<dim3(NB_B), bc, 0, stream>>>(
                rs, xs, Ap, pcur, rtrI, ptapI, rtrS + (size_t)(i + 1) * SCALSZ);
        }
        ep_sk<<<dim3(NB_B), bc, 0, stream>>>(
            rs, pB, ps, rtrS + (size_t)99 * SCALSZ, rtrS + (size_t)100 * SCALSZ);
    }
}